// Round 1
// baseline (200.743 us; speedup 1.0000x reference)
//
#include <hip/hip_runtime.h>
#include <stdint.h>

// Problem constants (match reference)
#define NN      4096
#define IN_DIM  1024
#define HID     128
#define RF      896          // (2^(K+1)-1)*HID
#define NW      128          // words per bitmask row (4096/32)

// ---------------------------------------------------------------------------
// 1) scatter edges into bitmask adjacency  A[src][dst] = 1
__global__ void scatter_edges(const int* __restrict__ ei, uint32_t* __restrict__ Abits, int nE) {
    int e = blockIdx.x * blockDim.x + threadIdx.x;
    if (e < nE) {
        int s = ei[e];
        int d = ei[nE + e];
        atomicOr(&Abits[(size_t)s * NW + (d >> 5)], 1u << (d & 31));
    }
}

// ---------------------------------------------------------------------------
// 2) 2-hop path counts -> A2 mask bits; also d1,d2 = rsqrt(deg+1e-8)
//    Block = 128 threads, one block per row i. Thread t owns j in [32t,32t+32).
__global__ void twohop(const uint32_t* __restrict__ Abits, uint32_t* __restrict__ A2bits,
                       float* __restrict__ d1, float* __restrict__ d2) {
    __shared__ uint16_t cnt[NN];       // 8 KB
    __shared__ uint32_t rowbits[NW];   // 512 B
    __shared__ int red[2][2];

    int i = blockIdx.x;
    int t = threadIdx.x;  // 0..127

    for (int j = t; j < NN; j += 128) cnt[j] = 0;
    rowbits[t] = Abits[(size_t)i * NW + t];
    __syncthreads();

    // For each neighbor k of i, add row k of A into cnt (thread t handles word t)
    for (int w = 0; w < NW; ++w) {
        uint32_t bits = rowbits[w];
        while (bits) {
            int b = __ffs(bits) - 1;
            bits &= bits - 1;
            int k = w * 32 + b;
            uint32_t kw = Abits[(size_t)k * NW + t];
            while (kw) {
                int bb = __ffs(kw) - 1;
                kw &= kw - 1;
                cnt[t * 32 + bb]++;
            }
        }
    }
    __syncthreads();

    // finalize: A2[i][j] = (cnt[j] - A[i][j] - (i==j)) > 0
    uint32_t self = rowbits[t];
    uint32_t m2 = 0;
    int pc2 = 0;
    #pragma unroll
    for (int b = 0; b < 32; ++b) {
        int j = t * 32 + b;
        int c = (int)cnt[j] - (int)((self >> b) & 1u) - (j == i ? 1 : 0);
        if (c > 0) { m2 |= (1u << b); pc2++; }
    }
    A2bits[(size_t)i * NW + t] = m2;

    int pc1 = __popc(self);
    #pragma unroll
    for (int off = 32; off; off >>= 1) {
        pc1 += __shfl_down(pc1, off);
        pc2 += __shfl_down(pc2, off);
    }
    if ((t & 63) == 0) { red[t >> 6][0] = pc1; red[t >> 6][1] = pc2; }
    __syncthreads();
    if (t == 0) {
        float deg1 = (float)(red[0][0] + red[1][0]);
        float deg2 = (float)(red[0][1] + red[1][1]);
        d1[i] = rsqrtf(deg1 + 1e-8f);
        d2[i] = rsqrtf(deg2 + 1e-8f);
    }
}

// ---------------------------------------------------------------------------
// 3) embed GEMM: rf[:,0:128] = relu(X @ W + b)   M=4096 K=1024 N=128, fp32
//    BM=16, BK=32, 256 threads, 2x4 micro-tile. Grid = 256 blocks.
__global__ void embed_gemm(const float* __restrict__ X, const float* __restrict__ W,
                           const float* __restrict__ bias, float* __restrict__ rf) {
    __shared__ __align__(16) float Xs[16][33];
    __shared__ __align__(16) float Ws[32][HID];

    int t  = threadIdx.x;
    int bm = blockIdx.x * 16;
    int r0 = (t >> 5) * 2;       // 0..14
    int c0 = (t & 31) * 4;       // 0..124

    float acc[2][4] = {};

    int xr = t >> 5, xc = t & 31;        // Xs load coords
    int wc = t & 127, wr = t >> 7;       // Ws load coords

    for (int kk = 0; kk < IN_DIM; kk += 32) {
        Xs[xr][xc]     = X[(size_t)(bm + xr) * IN_DIM + kk + xc];
        Xs[xr + 8][xc] = X[(size_t)(bm + xr + 8) * IN_DIM + kk + xc];
        #pragma unroll
        for (int p = 0; p < 16; ++p)
            Ws[wr + p * 2][wc] = W[(size_t)(kk + wr + p * 2) * HID + wc];
        __syncthreads();

        #pragma unroll
        for (int k = 0; k < 32; ++k) {
            float a0 = Xs[r0][k];
            float a1 = Xs[r0 + 1][k];
            float4 bv = *reinterpret_cast<const float4*>(&Ws[k][c0]);
            acc[0][0] += a0 * bv.x; acc[0][1] += a0 * bv.y;
            acc[0][2] += a0 * bv.z; acc[0][3] += a0 * bv.w;
            acc[1][0] += a1 * bv.x; acc[1][1] += a1 * bv.y;
            acc[1][2] += a1 * bv.z; acc[1][3] += a1 * bv.w;
        }
        __syncthreads();
    }

    #pragma unroll
    for (int rr = 0; rr < 2; ++rr)
        #pragma unroll
        for (int cc = 0; cc < 4; ++cc) {
            float v = acc[rr][cc] + bias[c0 + cc];
            v = fmaxf(v, 0.0f);
            rf[(size_t)(bm + r0 + rr) * RF + c0 + cc] = v;
        }
}

// ---------------------------------------------------------------------------
// 4) SpMM from bitmask: rout[i][t] = d[i] * sum_{j in row i} d[j] * rin[j][t]
//    Block = C threads (C = slice width), one block per row.
template <int C>
__global__ void spmm_bits(const uint32_t* __restrict__ bits, const float* __restrict__ dvec,
                          const float* __restrict__ rin, float* __restrict__ rout) {
    __shared__ uint32_t rowbits[NW];
    __shared__ uint16_t list[NN];
    __shared__ int cntS;

    int i = blockIdx.x;
    int t = threadIdx.x;

    if (t == 0) cntS = 0;
    for (int w = t; w < NW; w += C) rowbits[w] = bits[(size_t)i * NW + w];
    __syncthreads();

    for (int w = t; w < NW; w += C) {
        uint32_t b = rowbits[w];
        while (b) {
            int bb = __ffs(b) - 1;
            b &= b - 1;
            int pos = atomicAdd(&cntS, 1);
            list[pos] = (uint16_t)(w * 32 + bb);
        }
    }
    __syncthreads();

    int n = cntS;
    float acc = 0.0f;
    #pragma unroll 4
    for (int m = 0; m < n; ++m) {
        int j = list[m];
        acc += dvec[j] * rin[(size_t)j * RF + t];
    }
    rout[(size_t)i * RF + t] = dvec[i] * acc;
}

// ---------------------------------------------------------------------------
// 5) classifier GEMM: out = rf @ Wc + bc   [4096,896]@[896,10]
//    wave per row, 4 waves per block.
__global__ void cls_gemm(const float* __restrict__ rf, const float* __restrict__ Wc,
                         const float* __restrict__ bc, float* __restrict__ out) {
    int wave = threadIdx.x >> 6;
    int lane = threadIdx.x & 63;
    int row  = blockIdx.x * 4 + wave;

    float acc[10] = {};
    for (int k = lane; k < RF; k += 64) {
        float x = rf[(size_t)row * RF + k];
        #pragma unroll
        for (int c = 0; c < 10; ++c) acc[c] += x * Wc[k * 10 + c];
    }
    #pragma unroll
    for (int c = 0; c < 10; ++c)
        #pragma unroll
        for (int off = 32; off; off >>= 1) acc[c] += __shfl_down(acc[c], off);

    if (lane == 0) {
        #pragma unroll
        for (int c = 0; c < 10; ++c) out[(size_t)row * 10 + c] = acc[c] + bc[c];
    }
}

// ---------------------------------------------------------------------------
extern "C" void kernel_launch(void* const* d_in, const int* in_sizes, int n_in,
                              void* d_out, int out_size, void* d_ws, size_t ws_size,
                              hipStream_t stream) {
    const float* X       = (const float*)d_in[0];
    const int*   ei      = (const int*)d_in[1];      // edge_index, [2, nE]
    const float* W_embed = (const float*)d_in[2];
    const float* b_embed = (const float*)d_in[3];
    const float* W_cls   = (const float*)d_in[4];
    const float* b_cls   = (const float*)d_in[5];
    float* out = (float*)d_out;

    int nE = in_sizes[1] / 2;

    // workspace layout
    uint32_t* Abits  = (uint32_t*)d_ws;              // 2 MB
    uint32_t* A2bits = Abits + (size_t)NN * NW;      // 2 MB
    float* d1 = (float*)(A2bits + (size_t)NN * NW);  // 16 KB
    float* d2 = d1 + NN;                             // 16 KB
    float* rf = d2 + NN;                             // 4096*896*4 = 14.7 MB

    hipMemsetAsync(Abits, 0, (size_t)NN * NW * sizeof(uint32_t), stream);

    scatter_edges<<<(nE + 255) / 256, 256, 0, stream>>>(ei, Abits, nE);
    twohop<<<NN, 128, 0, stream>>>(Abits, A2bits, d1, d2);
    embed_gemm<<<NN / 16, 256, 0, stream>>>(X, W_embed, b_embed, rf);

    // K=1: r1 = [A1@r0, A2@r0] -> cols 128:256, 256:384
    spmm_bits<128><<<NN, 128, 0, stream>>>(Abits,  d1, rf + 0,   rf + 128);
    spmm_bits<128><<<NN, 128, 0, stream>>>(A2bits, d2, rf + 0,   rf + 256);
    // K=2: r2 = [A1@r1, A2@r1] -> cols 384:640, 640:896
    spmm_bits<256><<<NN, 256, 0, stream>>>(Abits,  d1, rf + 128, rf + 384);
    spmm_bits<256><<<NN, 256, 0, stream>>>(A2bits, d2, rf + 128, rf + 640);

    cls_gemm<<<NN / 4, 256, 0, stream>>>(rf, W_cls, b_cls, out);
}

// Round 2
// 167.382 us; speedup vs baseline: 1.1993x; 1.1993x over previous
//
#include <hip/hip_runtime.h>
#include <hip/hip_bf16.h>
#include <stdint.h>

// Problem constants (match reference)
#define NN      4096
#define IN_DIM  1024
#define HID     128
#define RF      896          // (2^(K+1)-1)*HID
#define NW      128          // words per bitmask row (4096/32)
#define CAP     2048         // max neighbors per row we list (2-hop mean ~256)

static __device__ __forceinline__ uint16_t f2bf(float f) {
    __hip_bfloat16 h = __float2bfloat16(f);   // RNE
    return *reinterpret_cast<uint16_t*>(&h);
}

// ---------------------------------------------------------------------------
// 1) scatter edges into bitmask adjacency  A[src][dst] = 1
__global__ void scatter_edges(const int* __restrict__ ei, uint32_t* __restrict__ Abits, int nE) {
    int e = blockIdx.x * blockDim.x + threadIdx.x;
    if (e < nE) {
        int s = ei[e];
        int d = ei[nE + e];
        atomicOr(&Abits[(size_t)s * NW + (d >> 5)], 1u << (d & 31));
    }
}

// ---------------------------------------------------------------------------
// 2) 2-hop path counts -> A2 mask bits; also d1,d2 = rsqrt(deg+1e-8)
__global__ void twohop(const uint32_t* __restrict__ Abits, uint32_t* __restrict__ A2bits,
                       float* __restrict__ d1, float* __restrict__ d2) {
    __shared__ uint16_t cnt[NN];       // 8 KB
    __shared__ uint32_t rowbits[NW];   // 512 B
    __shared__ int red[2][2];

    int i = blockIdx.x;
    int t = threadIdx.x;  // 0..127

    for (int j = t; j < NN; j += 128) cnt[j] = 0;
    rowbits[t] = Abits[(size_t)i * NW + t];
    __syncthreads();

    for (int w = 0; w < NW; ++w) {
        uint32_t bits = rowbits[w];
        while (bits) {
            int b = __ffs(bits) - 1;
            bits &= bits - 1;
            int k = w * 32 + b;
            uint32_t kw = Abits[(size_t)k * NW + t];
            while (kw) {
                int bb = __ffs(kw) - 1;
                kw &= kw - 1;
                cnt[t * 32 + bb]++;
            }
        }
    }
    __syncthreads();

    uint32_t self = rowbits[t];
    uint32_t m2 = 0;
    int pc2 = 0;
    #pragma unroll
    for (int b = 0; b < 32; ++b) {
        int j = t * 32 + b;
        int c = (int)cnt[j] - (int)((self >> b) & 1u) - (j == i ? 1 : 0);
        if (c > 0) { m2 |= (1u << b); pc2++; }
    }
    A2bits[(size_t)i * NW + t] = m2;

    int pc1 = __popc(self);
    #pragma unroll
    for (int off = 32; off; off >>= 1) {
        pc1 += __shfl_down(pc1, off);
        pc2 += __shfl_down(pc2, off);
    }
    if ((t & 63) == 0) { red[t >> 6][0] = pc1; red[t >> 6][1] = pc2; }
    __syncthreads();
    if (t == 0) {
        float deg1 = (float)(red[0][0] + red[1][0]);
        float deg2 = (float)(red[0][1] + red[1][1]);
        d1[i] = rsqrtf(deg1 + 1e-8f);
        d2[i] = rsqrtf(deg2 + 1e-8f);
    }
}

// ---------------------------------------------------------------------------
// 3) embed GEMM: r0 = relu(X @ W + b); write fp32 to rf[:,0:128] and
//    bf16 pre-scaled copies P1_0 = d1*r0, P2_0 = d2*r0 (stride 128).
__global__ void embed_gemm(const float* __restrict__ X, const float* __restrict__ W,
                           const float* __restrict__ bias, float* __restrict__ rf,
                           const float* __restrict__ d1, const float* __restrict__ d2,
                           uint16_t* __restrict__ P1, uint16_t* __restrict__ P2) {
    __shared__ __align__(16) float Xs[16][33];
    __shared__ __align__(16) float Ws[32][HID];

    int t  = threadIdx.x;
    int bm = blockIdx.x * 16;
    int r0 = (t >> 5) * 2;       // 0..14
    int c0 = (t & 31) * 4;       // 0..124

    float acc[2][4] = {};

    int xr = t >> 5, xc = t & 31;
    int wc = t & 127, wr = t >> 7;

    for (int kk = 0; kk < IN_DIM; kk += 32) {
        Xs[xr][xc]     = X[(size_t)(bm + xr) * IN_DIM + kk + xc];
        Xs[xr + 8][xc] = X[(size_t)(bm + xr + 8) * IN_DIM + kk + xc];
        #pragma unroll
        for (int p = 0; p < 16; ++p)
            Ws[wr + p * 2][wc] = W[(size_t)(kk + wr + p * 2) * HID + wc];
        __syncthreads();

        #pragma unroll
        for (int k = 0; k < 32; ++k) {
            float a0 = Xs[r0][k];
            float a1 = Xs[r0 + 1][k];
            float4 bv = *reinterpret_cast<const float4*>(&Ws[k][c0]);
            acc[0][0] += a0 * bv.x; acc[0][1] += a0 * bv.y;
            acc[0][2] += a0 * bv.z; acc[0][3] += a0 * bv.w;
            acc[1][0] += a1 * bv.x; acc[1][1] += a1 * bv.y;
            acc[1][2] += a1 * bv.z; acc[1][3] += a1 * bv.w;
        }
        __syncthreads();
    }

    #pragma unroll
    for (int rr = 0; rr < 2; ++rr) {
        int row = bm + r0 + rr;
        float s1 = d1[row], s2 = d2[row];
        #pragma unroll
        for (int cc = 0; cc < 4; ++cc) {
            float v = fmaxf(acc[rr][cc] + bias[c0 + cc], 0.0f);
            rf[(size_t)row * RF + c0 + cc] = v;
            P1[(size_t)row * HID + c0 + cc] = f2bf(s1 * v);
            P2[(size_t)row * HID + c0 + cc] = f2bf(s2 * v);
        }
    }
}

// ---------------------------------------------------------------------------
// 4) SpMM gather from bitmask, bf16 pre-scaled operand.
//    Wave-per-row, 4 waves/block. W = uint words (bf16 pairs) per lane.
//    C = 128*W columns.  rout[i][c] = dout[i] * sum_{j in row} P[j][c]
//    Optional bf16 outputs Q1 = dq1[i]*rout_row, Q2 = dq2[i]*rout_row (stride qs).
template <int W>
__global__ __launch_bounds__(256) void spmm_gather(
    const uint32_t* __restrict__ bits, const float* __restrict__ dout,
    const uint16_t* __restrict__ P, float* __restrict__ rout,
    uint16_t* __restrict__ Q1, const float* __restrict__ dq1,
    uint16_t* __restrict__ Q2, const float* __restrict__ dq2, int qs)
{
    __shared__ uint16_t list[4][CAP];
    __shared__ int cnt[4];

    int wv   = threadIdx.x >> 6;
    int lane = threadIdx.x & 63;
    int i    = blockIdx.x * 4 + wv;

    if (lane == 0) cnt[wv] = 0;
    uint2 rb = *reinterpret_cast<const uint2*>(&bits[(size_t)i * NW + lane * 2]);
    __syncthreads();

    uint32_t b0 = rb.x, b1 = rb.y;
    int base = lane * 64;
    while (b0) {
        int bb = __ffs(b0) - 1; b0 &= b0 - 1;
        int pos = atomicAdd(&cnt[wv], 1);
        list[wv][pos] = (uint16_t)(base + bb);
    }
    while (b1) {
        int bb = __ffs(b1) - 1; b1 &= b1 - 1;
        int pos = atomicAdd(&cnt[wv], 1);
        list[wv][pos] = (uint16_t)(base + 32 + bb);
    }
    __syncthreads();

    const int n = cnt[wv];
    const uint32_t* Pp = reinterpret_cast<const uint32_t*>(P);
    float acc[2 * W] = {};

    if constexpr (W == 1) {
        #pragma unroll 8
        for (int m = 0; m < n; ++m) {
            int j = list[wv][m];
            uint32_t u = Pp[(size_t)j * 64 + lane];
            acc[0] += __uint_as_float(u << 16);
            acc[1] += __uint_as_float(u & 0xffff0000u);
        }
    } else {
        #pragma unroll 8
        for (int m = 0; m < n; ++m) {
            int j = list[wv][m];
            uint2 u = *reinterpret_cast<const uint2*>(Pp + (size_t)j * 128 + lane * 2);
            acc[0] += __uint_as_float(u.x << 16);
            acc[1] += __uint_as_float(u.x & 0xffff0000u);
            acc[2] += __uint_as_float(u.y << 16);
            acc[3] += __uint_as_float(u.y & 0xffff0000u);
        }
    }

    float di = dout[i];
    if constexpr (W == 1) {
        float2 o; o.x = di * acc[0]; o.y = di * acc[1];
        *reinterpret_cast<float2*>(rout + (size_t)i * RF + lane * 2) = o;
        if (Q1) {
            float s1 = dq1[i], s2 = dq2[i];
            ushort2 q;
            q.x = f2bf(s1 * o.x); q.y = f2bf(s1 * o.y);
            *reinterpret_cast<ushort2*>(Q1 + (size_t)i * qs + lane * 2) = q;
            q.x = f2bf(s2 * o.x); q.y = f2bf(s2 * o.y);
            *reinterpret_cast<ushort2*>(Q2 + (size_t)i * qs + lane * 2) = q;
        }
    } else {
        float4 o;
        o.x = di * acc[0]; o.y = di * acc[1];
        o.z = di * acc[2]; o.w = di * acc[3];
        *reinterpret_cast<float4*>(rout + (size_t)i * RF + lane * 4) = o;
        // (Q outputs unused for the last hop)
    }
}

// ---------------------------------------------------------------------------
// 5) classifier GEMM: out = rf @ Wc + bc   [4096,896]@[896,10]
__global__ void cls_gemm(const float* __restrict__ rf, const float* __restrict__ Wc,
                         const float* __restrict__ bc, float* __restrict__ out) {
    int wave = threadIdx.x >> 6;
    int lane = threadIdx.x & 63;
    int row  = blockIdx.x * 4 + wave;

    float acc[10] = {};
    for (int k = lane; k < RF; k += 64) {
        float x = rf[(size_t)row * RF + k];
        #pragma unroll
        for (int c = 0; c < 10; ++c) acc[c] += x * Wc[k * 10 + c];
    }
    #pragma unroll
    for (int c = 0; c < 10; ++c)
        #pragma unroll
        for (int off = 32; off; off >>= 1) acc[c] += __shfl_down(acc[c], off);

    if (lane == 0) {
        #pragma unroll
        for (int c = 0; c < 10; ++c) out[(size_t)row * 10 + c] = acc[c] + bc[c];
    }
}

// ---------------------------------------------------------------------------
extern "C" void kernel_launch(void* const* d_in, const int* in_sizes, int n_in,
                              void* d_out, int out_size, void* d_ws, size_t ws_size,
                              hipStream_t stream) {
    const float* X       = (const float*)d_in[0];
    const int*   ei      = (const int*)d_in[1];
    const float* W_embed = (const float*)d_in[2];
    const float* b_embed = (const float*)d_in[3];
    const float* W_cls   = (const float*)d_in[4];
    const float* b_cls   = (const float*)d_in[5];
    float* out = (float*)d_out;

    int nE = in_sizes[1] / 2;

    // workspace layout
    uint32_t* Abits  = (uint32_t*)d_ws;                    // 2 MB
    uint32_t* A2bits = Abits + (size_t)NN * NW;            // 2 MB
    float* d1 = (float*)(A2bits + (size_t)NN * NW);        // 16 KB
    float* d2 = d1 + NN;                                   // 16 KB
    float* rf = d2 + NN;                                   // 14.68 MB fp32 [NN][RF]
    uint16_t* P1_0 = (uint16_t*)(rf + (size_t)NN * RF);    // 1 MB  bf16 [NN][128] = d1*r0
    uint16_t* P2_0 = P1_0 + (size_t)NN * HID;              // 1 MB  bf16 [NN][128] = d2*r0
    uint16_t* P1_1 = P2_0 + (size_t)NN * HID;              // 2 MB  bf16 [NN][256] = d1*r1
    uint16_t* P2_1 = P1_1 + (size_t)NN * 256;              // 2 MB  bf16 [NN][256] = d2*r1

    hipMemsetAsync(Abits, 0, (size_t)NN * NW * sizeof(uint32_t), stream);

    scatter_edges<<<(nE + 255) / 256, 256, 0, stream>>>(ei, Abits, nE);
    twohop<<<NN, 128, 0, stream>>>(Abits, A2bits, d1, d2);
    embed_gemm<<<NN / 16, 256, 0, stream>>>(X, W_embed, b_embed, rf, d1, d2, P1_0, P2_0);

    // K=1: r1 = [A1@r0 (cols 128:256), A2@r0 (cols 256:384)], also emit P1_1/P2_1
    spmm_gather<1><<<NN / 4, 256, 0, stream>>>(Abits,  d1, P1_0, rf + 128,
                                               P1_1,       d1, P2_1,       d2, 256);
    spmm_gather<1><<<NN / 4, 256, 0, stream>>>(A2bits, d2, P2_0, rf + 256,
                                               P1_1 + 128, d1, P2_1 + 128, d2, 256);
    // K=2: r2 = [A1@r1 (cols 384:640), A2@r1 (cols 640:896)]
    spmm_gather<2><<<NN / 4, 256, 0, stream>>>(Abits,  d1, P1_1, rf + 384,
                                               nullptr, nullptr, nullptr, nullptr, 0);
    spmm_gather<2><<<NN / 4, 256, 0, stream>>>(A2bits, d2, P2_1, rf + 640,
                                               nullptr, nullptr, nullptr, nullptr, 0);

    cls_gemm<<<NN / 4, 256, 0, stream>>>(rf, W_cls, b_cls, out);
}

// Round 3
// 145.611 us; speedup vs baseline: 1.3786x; 1.1495x over previous
//
#include <hip/hip_runtime.h>
#include <hip/hip_bf16.h>
#include <stdint.h>

// Problem constants (match reference)
#define NN      4096
#define IN_DIM  1024
#define HID     128
#define RF      896          // (2^(K+1)-1)*HID
#define NW      128          // words per bitmask row (4096/32)
#define CAP     2048         // max neighbors per row we list
#define KS      8            // split-K chunks for embed gemm
#define KC      (IN_DIM/KS)  // 128

typedef __attribute__((ext_vector_type(8))) short   bf16x8;
typedef __attribute__((ext_vector_type(4))) float   f32x4;

static __device__ __forceinline__ uint16_t f2bf(float f) {
    __hip_bfloat16 h = __float2bfloat16(f);   // RNE
    return *reinterpret_cast<uint16_t*>(&h);
}
static __device__ __forceinline__ float bf2f(uint16_t u) {
    __hip_bfloat16 h = *reinterpret_cast<__hip_bfloat16*>(&u);
    return __bfloat162float(h);
}

// ---------------------------------------------------------------------------
// 1) scatter edges into bitmask adjacency  A[src][dst] = 1
__global__ void scatter_edges(const int* __restrict__ ei, uint32_t* __restrict__ Abits, int nE) {
    int e = blockIdx.x * blockDim.x + threadIdx.x;
    if (e < nE) {
        int s = ei[e];
        int d = ei[nE + e];
        atomicOr(&Abits[(size_t)s * NW + (d >> 5)], 1u << (d & 31));
    }
}

// ---------------------------------------------------------------------------
// 2) 2-hop path counts -> A2 mask bits; also d1,d2 = rsqrt(deg+1e-8)
__global__ void twohop(const uint32_t* __restrict__ Abits, uint32_t* __restrict__ A2bits,
                       float* __restrict__ d1, float* __restrict__ d2) {
    __shared__ uint16_t cnt[NN];       // 8 KB
    __shared__ uint32_t rowbits[NW];   // 512 B
    __shared__ int red[2][2];

    int i = blockIdx.x;
    int t = threadIdx.x;  // 0..127

    for (int j = t; j < NN; j += 128) cnt[j] = 0;
    rowbits[t] = Abits[(size_t)i * NW + t];
    __syncthreads();

    for (int w = 0; w < NW; ++w) {
        uint32_t bits = rowbits[w];
        while (bits) {
            int b = __ffs(bits) - 1;
            bits &= bits - 1;
            int k = w * 32 + b;
            uint32_t kw = Abits[(size_t)k * NW + t];
            while (kw) {
                int bb = __ffs(kw) - 1;
                kw &= kw - 1;
                cnt[t * 32 + bb]++;
            }
        }
    }
    __syncthreads();

    uint32_t self = rowbits[t];
    uint32_t m2 = 0;
    int pc2 = 0;
    #pragma unroll
    for (int b = 0; b < 32; ++b) {
        int j = t * 32 + b;
        int c = (int)cnt[j] - (int)((self >> b) & 1u) - (j == i ? 1 : 0);
        if (c > 0) { m2 |= (1u << b); pc2++; }
    }
    A2bits[(size_t)i * NW + t] = m2;

    int pc1 = __popc(self);
    #pragma unroll
    for (int off = 32; off; off >>= 1) {
        pc1 += __shfl_down(pc1, off);
        pc2 += __shfl_down(pc2, off);
    }
    if ((t & 63) == 0) { red[t >> 6][0] = pc1; red[t >> 6][1] = pc2; }
    __syncthreads();
    if (t == 0) {
        float deg1 = (float)(red[0][0] + red[1][0]);
        float deg2 = (float)(red[0][1] + red[1][1]);
        d1[i] = rsqrtf(deg1 + 1e-8f);
        d2[i] = rsqrtf(deg2 + 1e-8f);
    }
}

// ---------------------------------------------------------------------------
// 3a) convert W -> transposed bf16 hi/lo:  Wt[n][k] = bf16 split of W[k][n]
//     grid 128 blocks (k-groups of 8), 128 threads (= n)
__global__ void convert_w(const float* __restrict__ W,
                          uint16_t* __restrict__ Wt_hi, uint16_t* __restrict__ Wt_lo) {
    int n  = threadIdx.x;
    int k0 = blockIdx.x * 8;
    uint16_t h[8], l[8];
    #pragma unroll
    for (int j = 0; j < 8; ++j) {
        float x = W[(size_t)(k0 + j) * HID + n];
        h[j] = f2bf(x);
        l[j] = f2bf(x - bf2f(h[j]));
    }
    ushort4* ph = reinterpret_cast<ushort4*>(Wt_hi + (size_t)n * IN_DIM + k0);
    ushort4* pl = reinterpret_cast<ushort4*>(Wt_lo + (size_t)n * IN_DIM + k0);
    ph[0] = make_ushort4(h[0], h[1], h[2], h[3]);
    ph[1] = make_ushort4(h[4], h[5], h[6], h[7]);
    pl[0] = make_ushort4(l[0], l[1], l[2], l[3]);
    pl[1] = make_ushort4(l[4], l[5], l[6], l[7]);
}

// ---------------------------------------------------------------------------
// 3b) embed MFMA GEMM, bf16x2 split, split-K.
//     grid (128, KS), 128 threads (2 waves). Block tile: 32 rows x 128 cols x KC.
//     partials[kc][row][col] fp32.
#define XSTR 136   // padded LDS stride (shorts): 272 B, 16-aligned, 2-way bank alias
__global__ __launch_bounds__(128) void embed_mfma(
    const float* __restrict__ X, const uint16_t* __restrict__ Wt_hi,
    const uint16_t* __restrict__ Wt_lo, float* __restrict__ partials)
{
    __shared__ uint16_t XhiS[32][XSTR];
    __shared__ uint16_t XloS[32][XSTR];
    __shared__ uint16_t WS[128][XSTR];

    int t  = threadIdx.x;
    int m0 = blockIdx.x * 32;
    int kc = blockIdx.y;

    // stage X tile (32 x KC fp32) -> hi/lo bf16
    #pragma unroll
    for (int u = 0; u < 8; ++u) {
        int q = u * 128 + t;
        int row = q >> 5, c4 = q & 31;
        float4 xv = *reinterpret_cast<const float4*>(
            X + (size_t)(m0 + row) * IN_DIM + kc * KC + c4 * 4);
        ushort4 hv, lv;
        hv.x = f2bf(xv.x); lv.x = f2bf(xv.x - bf2f(hv.x));
        hv.y = f2bf(xv.y); lv.y = f2bf(xv.y - bf2f(hv.y));
        hv.z = f2bf(xv.z); lv.z = f2bf(xv.z - bf2f(hv.z));
        hv.w = f2bf(xv.w); lv.w = f2bf(xv.w - bf2f(hv.w));
        *reinterpret_cast<ushort4*>(&XhiS[row][c4 * 4]) = hv;
        *reinterpret_cast<ushort4*>(&XloS[row][c4 * 4]) = lv;
    }
    // stage W_hi tile (128 n x KC k bf16)
    #pragma unroll
    for (int u = 0; u < 16; ++u) {
        int q = u * 128 + t;
        int n = q >> 4, ck = q & 15;
        *reinterpret_cast<uint4*>(&WS[n][ck * 8]) =
            *reinterpret_cast<const uint4*>(Wt_hi + (size_t)n * IN_DIM + kc * KC + ck * 8);
    }
    __syncthreads();

    int w = t >> 6, lane = t & 63;
    int nr = lane & 15, g = lane >> 4;
    int arow = w * 16 + nr;

    bf16x8 ah[4], al[4];
    #pragma unroll
    for (int s = 0; s < 4; ++s) {
        ah[s] = *reinterpret_cast<const bf16x8*>(&XhiS[arow][s * 32 + g * 8]);
        al[s] = *reinterpret_cast<const bf16x8*>(&XloS[arow][s * 32 + g * 8]);
    }

    f32x4 acc[8] = {};

    // phase 1: Xhi@Whi + Xlo@Whi
    #pragma unroll
    for (int s = 0; s < 4; ++s)
        #pragma unroll
        for (int nf = 0; nf < 8; ++nf) {
            bf16x8 b = *reinterpret_cast<const bf16x8*>(&WS[nf * 16 + nr][s * 32 + g * 8]);
            acc[nf] = __builtin_amdgcn_mfma_f32_16x16x32_bf16(ah[s], b, acc[nf], 0, 0, 0);
            acc[nf] = __builtin_amdgcn_mfma_f32_16x16x32_bf16(al[s], b, acc[nf], 0, 0, 0);
        }
    __syncthreads();
    // stage W_lo
    #pragma unroll
    for (int u = 0; u < 16; ++u) {
        int q = u * 128 + t;
        int n = q >> 4, ck = q & 15;
        *reinterpret_cast<uint4*>(&WS[n][ck * 8]) =
            *reinterpret_cast<const uint4*>(Wt_lo + (size_t)n * IN_DIM + kc * KC + ck * 8);
    }
    __syncthreads();
    // phase 2: Xhi@Wlo
    #pragma unroll
    for (int s = 0; s < 4; ++s)
        #pragma unroll
        for (int nf = 0; nf < 8; ++nf) {
            bf16x8 b = *reinterpret_cast<const bf16x8*>(&WS[nf * 16 + nr][s * 32 + g * 8]);
            acc[nf] = __builtin_amdgcn_mfma_f32_16x16x32_bf16(ah[s], b, acc[nf], 0, 0, 0);
        }

    // write partials: D row = g*4+r, col = nr (per 16x16 frag nf)
    float* part = partials + (size_t)kc * NN * HID;
    #pragma unroll
    for (int nf = 0; nf < 8; ++nf)
        #pragma unroll
        for (int r = 0; r < 4; ++r)
            part[(size_t)(m0 + w * 16 + g * 4 + r) * HID + nf * 16 + nr] = acc[nf][r];
}

// ---------------------------------------------------------------------------
// 3c) reduce split-K partials + bias + relu -> rf fp32, P1_0/P2_0 bf16 prescaled
__global__ void embed_reduce(const float* __restrict__ partials, const float* __restrict__ bias,
                             const float* __restrict__ d1, const float* __restrict__ d2,
                             float* __restrict__ rf, uint16_t* __restrict__ P1,
                             uint16_t* __restrict__ P2) {
    int idx = blockIdx.x * blockDim.x + threadIdx.x;   // float4 index
    size_t off = (size_t)idx * 4;
    int row = (int)(off >> 7);
    int col = (int)(off & 127);

    float4 s = make_float4(0.f, 0.f, 0.f, 0.f);
    #pragma unroll
    for (int kc = 0; kc < KS; ++kc) {
        float4 p = *reinterpret_cast<const float4*>(partials + (size_t)kc * NN * HID + off);
        s.x += p.x; s.y += p.y; s.z += p.z; s.w += p.w;
    }
    float4 bv = *reinterpret_cast<const float4*>(bias + col);
    float4 v;
    v.x = fmaxf(s.x + bv.x, 0.f);
    v.y = fmaxf(s.y + bv.y, 0.f);
    v.z = fmaxf(s.z + bv.z, 0.f);
    v.w = fmaxf(s.w + bv.w, 0.f);
    *reinterpret_cast<float4*>(rf + (size_t)row * RF + col) = v;

    float s1 = d1[row], s2 = d2[row];
    ushort4 q;
    q.x = f2bf(s1 * v.x); q.y = f2bf(s1 * v.y); q.z = f2bf(s1 * v.z); q.w = f2bf(s1 * v.w);
    *reinterpret_cast<ushort4*>(P1 + (size_t)row * HID + col) = q;
    q.x = f2bf(s2 * v.x); q.y = f2bf(s2 * v.y); q.z = f2bf(s2 * v.z); q.w = f2bf(s2 * v.w);
    *reinterpret_cast<ushort4*>(P2 + (size_t)row * HID + col) = q;
}

// ---------------------------------------------------------------------------
// 4) SpMM gather from bitmask, bf16 pre-scaled operand (wave-per-row).
template <int W>
__global__ __launch_bounds__(256) void spmm_gather(
    const uint32_t* __restrict__ bits, const float* __restrict__ dout,
    const uint16_t* __restrict__ P, float* __restrict__ rout,
    uint16_t* __restrict__ Q1, const float* __restrict__ dq1,
    uint16_t* __restrict__ Q2, const float* __restrict__ dq2, int qs)
{
    __shared__ uint16_t list[4][CAP];
    __shared__ int cnt[4];

    int wv   = threadIdx.x >> 6;
    int lane = threadIdx.x & 63;
    int i    = blockIdx.x * 4 + wv;

    if (lane == 0) cnt[wv] = 0;
    uint2 rb = *reinterpret_cast<const uint2*>(&bits[(size_t)i * NW + lane * 2]);
    __syncthreads();

    uint32_t b0 = rb.x, b1 = rb.y;
    int base = lane * 64;
    while (b0) {
        int bb = __ffs(b0) - 1; b0 &= b0 - 1;
        int pos = atomicAdd(&cnt[wv], 1);
        list[wv][pos] = (uint16_t)(base + bb);
    }
    while (b1) {
        int bb = __ffs(b1) - 1; b1 &= b1 - 1;
        int pos = atomicAdd(&cnt[wv], 1);
        list[wv][pos] = (uint16_t)(base + 32 + bb);
    }
    __syncthreads();

    const int n = cnt[wv];
    const uint32_t* Pp = reinterpret_cast<const uint32_t*>(P);
    float acc[2 * W] = {};

    if constexpr (W == 1) {
        #pragma unroll 8
        for (int m = 0; m < n; ++m) {
            int j = list[wv][m];
            uint32_t u = Pp[(size_t)j * 64 + lane];
            acc[0] += __uint_as_float(u << 16);
            acc[1] += __uint_as_float(u & 0xffff0000u);
        }
    } else {
        #pragma unroll 8
        for (int m = 0; m < n; ++m) {
            int j = list[wv][m];
            uint2 u = *reinterpret_cast<const uint2*>(Pp + (size_t)j * 128 + lane * 2);
            acc[0] += __uint_as_float(u.x << 16);
            acc[1] += __uint_as_float(u.x & 0xffff0000u);
            acc[2] += __uint_as_float(u.y << 16);
            acc[3] += __uint_as_float(u.y & 0xffff0000u);
        }
    }

    float di = dout[i];
    if constexpr (W == 1) {
        float2 o; o.x = di * acc[0]; o.y = di * acc[1];
        *reinterpret_cast<float2*>(rout + (size_t)i * RF + lane * 2) = o;
        if (Q1) {
            float s1 = dq1[i], s2 = dq2[i];
            ushort2 q;
            q.x = f2bf(s1 * o.x); q.y = f2bf(s1 * o.y);
            *reinterpret_cast<ushort2*>(Q1 + (size_t)i * qs + lane * 2) = q;
            q.x = f2bf(s2 * o.x); q.y = f2bf(s2 * o.y);
            *reinterpret_cast<ushort2*>(Q2 + (size_t)i * qs + lane * 2) = q;
        }
    } else {
        float4 o;
        o.x = di * acc[0]; o.y = di * acc[1];
        o.z = di * acc[2]; o.w = di * acc[3];
        *reinterpret_cast<float4*>(rout + (size_t)i * RF + lane * 4) = o;
    }
}

// ---------------------------------------------------------------------------
// 5) classifier GEMM: out = rf @ Wc + bc   [4096,896]@[896,10]
__global__ void cls_gemm(const float* __restrict__ rf, const float* __restrict__ Wc,
                         const float* __restrict__ bc, float* __restrict__ out) {
    int wave = threadIdx.x >> 6;
    int lane = threadIdx.x & 63;
    int row  = blockIdx.x * 4 + wave;

    float acc[10] = {};
    for (int k = lane; k < RF; k += 64) {
        float x = rf[(size_t)row * RF + k];
        #pragma unroll
        for (int c = 0; c < 10; ++c) acc[c] += x * Wc[k * 10 + c];
    }
    #pragma unroll
    for (int c = 0; c < 10; ++c)
        #pragma unroll
        for (int off = 32; off; off >>= 1) acc[c] += __shfl_down(acc[c], off);

    if (lane == 0) {
        #pragma unroll
        for (int c = 0; c < 10; ++c) out[(size_t)row * 10 + c] = acc[c] + bc[c];
    }
}

// ---------------------------------------------------------------------------
extern "C" void kernel_launch(void* const* d_in, const int* in_sizes, int n_in,
                              void* d_out, int out_size, void* d_ws, size_t ws_size,
                              hipStream_t stream) {
    const float* X       = (const float*)d_in[0];
    const int*   ei      = (const int*)d_in[1];
    const float* W_embed = (const float*)d_in[2];
    const float* b_embed = (const float*)d_in[3];
    const float* W_cls   = (const float*)d_in[4];
    const float* b_cls   = (const float*)d_in[5];
    float* out = (float*)d_out;

    int nE = in_sizes[1] / 2;

    // workspace layout (all offsets 16B-aligned)
    uint32_t* Abits  = (uint32_t*)d_ws;                    // 2 MB
    uint32_t* A2bits = Abits + (size_t)NN * NW;            // 2 MB
    float* d1 = (float*)(A2bits + (size_t)NN * NW);        // 16 KB
    float* d2 = d1 + NN;                                   // 16 KB
    float* rf = d2 + NN;                                   // 14.68 MB fp32 [NN][RF]
    uint16_t* P1_0 = (uint16_t*)(rf + (size_t)NN * RF);    // 1 MB  bf16 [NN][128]
    uint16_t* P2_0 = P1_0 + (size_t)NN * HID;              // 1 MB
    uint16_t* P1_1 = P2_0 + (size_t)NN * HID;              // 2 MB  bf16 [NN][256]
    uint16_t* P2_1 = P1_1 + (size_t)NN * 256;              // 2 MB
    uint16_t* Wt_hi = P2_1 + (size_t)NN * 256;             // 256 KB bf16 [128][1024]
    uint16_t* Wt_lo = Wt_hi + (size_t)HID * IN_DIM;        // 256 KB
    float* partials = (float*)(Wt_lo + (size_t)HID * IN_DIM); // 16 MB f32 [KS][NN][128]

    hipMemsetAsync(Abits, 0, (size_t)NN * NW * sizeof(uint32_t), stream);

    scatter_edges<<<(nE + 255) / 256, 256, 0, stream>>>(ei, Abits, nE);
    twohop<<<NN, 128, 0, stream>>>(Abits, A2bits, d1, d2);

    convert_w<<<IN_DIM / 8, HID, 0, stream>>>(W_embed, Wt_hi, Wt_lo);
    embed_mfma<<<dim3(NN / 32, KS), 128, 0, stream>>>(X, Wt_hi, Wt_lo, partials);
    embed_reduce<<<(NN * HID / 4) / 256, 256, 0, stream>>>(partials, b_embed, d1, d2,
                                                           rf, P1_0, P2_0);

    // K=1: r1 = [A1@r0 (cols 128:256), A2@r0 (cols 256:384)], also emit P1_1/P2_1
    spmm_gather<1><<<NN / 4, 256, 0, stream>>>(Abits,  d1, P1_0, rf + 128,
                                               P1_1,       d1, P2_1,       d2, 256);
    spmm_gather<1><<<NN / 4, 256, 0, stream>>>(A2bits, d2, P2_0, rf + 256,
                                               P1_1 + 128, d1, P2_1 + 128, d2, 256);
    // K=2: r2 = [A1@r1 (cols 384:640), A2@r1 (cols 640:896)]
    spmm_gather<2><<<NN / 4, 256, 0, stream>>>(Abits,  d1, P1_1, rf + 384,
                                               nullptr, nullptr, nullptr, nullptr, 0);
    spmm_gather<2><<<NN / 4, 256, 0, stream>>>(A2bits, d2, P2_1, rf + 640,
                                               nullptr, nullptr, nullptr, nullptr, 0);

    cls_gemm<<<NN / 4, 256, 0, stream>>>(rf, W_cls, b_cls, out);
}

// Round 4
// 122.573 us; speedup vs baseline: 1.6377x; 1.1879x over previous
//
#include <hip/hip_runtime.h>
#include <hip/hip_bf16.h>
#include <stdint.h>

// Problem constants (match reference)
#define NN      4096
#define IN_DIM  1024
#define HID     128
#define RF      896          // (2^(K+1)-1)*HID
#define NW      128          // words per bitmask row (4096/32)
#define CAP1    64           // adj1 stride (1-hop deg ~16, max ~40)
#define CAP2    1024         // adj2 stride (2-hop deg ~240, max ~600)
#define KS      8            // split-K chunks for embed gemm
#define KC      (IN_DIM/KS)  // 128

typedef __attribute__((ext_vector_type(8))) short   bf16x8;
typedef __attribute__((ext_vector_type(4))) float   f32x4;

static __device__ __forceinline__ uint16_t f2bf(float f) {
    __hip_bfloat16 h = __float2bfloat16(f);   // RNE
    return *reinterpret_cast<uint16_t*>(&h);
}
static __device__ __forceinline__ float bf2f(uint16_t u) {
    __hip_bfloat16 h = *reinterpret_cast<__hip_bfloat16*>(&u);
    return __bfloat162float(h);
}
static __device__ __forceinline__ uint32_t packbf(float lo, float hi) {
    return (uint32_t)f2bf(lo) | ((uint32_t)f2bf(hi) << 16);
}

// ---------------------------------------------------------------------------
// 1) scatter edges into bitmask adjacency  A[src][dst] = 1
__global__ void scatter_edges(const int* __restrict__ ei, uint32_t* __restrict__ Abits, int nE) {
    int e = blockIdx.x * blockDim.x + threadIdx.x;
    if (e < nE) {
        int s = ei[e];
        int d = ei[nE + e];
        atomicOr(&Abits[(size_t)s * NW + (d >> 5)], 1u << (d & 31));
    }
}

// ---------------------------------------------------------------------------
// 1b) zero the pad row (row NN) of each P array
__global__ void zero_pads(uint32_t* p10, uint32_t* p20, uint32_t* p11, uint32_t* p21) {
    int t = threadIdx.x;  // 256
    if (t < 64)  { p10[(size_t)NN * 64 + t] = 0;  p20[(size_t)NN * 64 + t] = 0; }
    if (t < 128) { p11[(size_t)NN * 128 + t] = 0; p21[(size_t)NN * 128 + t] = 0; }
}

// ---------------------------------------------------------------------------
// 2) 2-hop path counts -> CSR adjacency lists (padded to x4 with sentinel NN)
//    + d1,d2 = rsqrt(deg+1e-8).  One block (128 thr) per row i.
__global__ void twohop(const uint32_t* __restrict__ Abits,
                       uint16_t* __restrict__ adj1, uint16_t* __restrict__ adj2,
                       int* __restrict__ deg1p, int* __restrict__ deg2p,
                       float* __restrict__ d1, float* __restrict__ d2) {
    __shared__ uint16_t cnt[NN];       // 8 KB
    __shared__ uint32_t rowbits[NW];   // 512 B
    __shared__ int wtot[2][2];

    int i = blockIdx.x;
    int t = threadIdx.x;  // 0..127
    int lane = t & 63, wv = t >> 6;

    for (int j = t; j < NN; j += 128) cnt[j] = 0;
    rowbits[t] = Abits[(size_t)i * NW + t];
    __syncthreads();

    for (int w = 0; w < NW; ++w) {
        uint32_t bits = rowbits[w];
        while (bits) {
            int b = __ffs(bits) - 1;
            bits &= bits - 1;
            int k = w * 32 + b;
            uint32_t kw = Abits[(size_t)k * NW + t];
            while (kw) {
                int bb = __ffs(kw) - 1;
                kw &= kw - 1;
                cnt[t * 32 + bb]++;
            }
        }
    }
    __syncthreads();

    uint32_t self = rowbits[t];
    uint32_t m2 = 0;
    #pragma unroll
    for (int b = 0; b < 32; ++b) {
        int j = t * 32 + b;
        int c = (int)cnt[j] - (int)((self >> b) & 1u) - (j == i ? 1 : 0);
        if (c > 0) m2 |= (1u << b);
    }

    int pc1 = __popc(self), pc2 = __popc(m2);
    // inclusive scan within wave (both counters)
    int x1 = pc1, x2 = pc2;
    #pragma unroll
    for (int off = 1; off < 64; off <<= 1) {
        int y1 = __shfl_up(x1, off), y2 = __shfl_up(x2, off);
        if (lane >= off) { x1 += y1; x2 += y2; }
    }
    if (lane == 63) { wtot[wv][0] = x1; wtot[wv][1] = x2; }
    __syncthreads();

    int b1 = (wv ? wtot[0][0] : 0) + x1 - pc1;   // exclusive prefix
    int b2 = (wv ? wtot[0][1] : 0) + x2 - pc2;

    uint32_t b = self; int o = b1;
    while (b) { int bb = __ffs(b) - 1; b &= b - 1; adj1[(size_t)i * CAP1 + o++] = (uint16_t)(t * 32 + bb); }
    b = m2; o = b2;
    while (b) { int bb = __ffs(b) - 1; b &= b - 1; adj2[(size_t)i * CAP2 + o++] = (uint16_t)(t * 32 + bb); }

    if (t == 0) {
        int tot1 = wtot[0][0] + wtot[1][0];
        int tot2 = wtot[0][1] + wtot[1][1];
        int n1 = (tot1 + 3) & ~3, n2 = (tot2 + 3) & ~3;
        for (int z = tot1; z < n1; ++z) adj1[(size_t)i * CAP1 + z] = (uint16_t)NN;
        for (int z = tot2; z < n2; ++z) adj2[(size_t)i * CAP2 + z] = (uint16_t)NN;
        deg1p[i] = n1; deg2p[i] = n2;
        d1[i] = rsqrtf((float)tot1 + 1e-8f);
        d2[i] = rsqrtf((float)tot2 + 1e-8f);
    }
}

// ---------------------------------------------------------------------------
// 3a) convert W -> transposed bf16 hi/lo
__global__ void convert_w(const float* __restrict__ W,
                          uint16_t* __restrict__ Wt_hi, uint16_t* __restrict__ Wt_lo) {
    int n  = threadIdx.x;
    int k0 = blockIdx.x * 8;
    uint16_t h[8], l[8];
    #pragma unroll
    for (int j = 0; j < 8; ++j) {
        float x = W[(size_t)(k0 + j) * HID + n];
        h[j] = f2bf(x);
        l[j] = f2bf(x - bf2f(h[j]));
    }
    ushort4* ph = reinterpret_cast<ushort4*>(Wt_hi + (size_t)n * IN_DIM + k0);
    ushort4* pl = reinterpret_cast<ushort4*>(Wt_lo + (size_t)n * IN_DIM + k0);
    ph[0] = make_ushort4(h[0], h[1], h[2], h[3]);
    ph[1] = make_ushort4(h[4], h[5], h[6], h[7]);
    pl[0] = make_ushort4(l[0], l[1], l[2], l[3]);
    pl[1] = make_ushort4(l[4], l[5], l[6], l[7]);
}

// ---------------------------------------------------------------------------
// 3b) embed MFMA GEMM, bf16x2 split, split-K
#define XSTR 136
__global__ __launch_bounds__(128) void embed_mfma(
    const float* __restrict__ X, const uint16_t* __restrict__ Wt_hi,
    const uint16_t* __restrict__ Wt_lo, float* __restrict__ partials)
{
    __shared__ uint16_t XhiS[32][XSTR];
    __shared__ uint16_t XloS[32][XSTR];
    __shared__ uint16_t WS[128][XSTR];

    int t  = threadIdx.x;
    int m0 = blockIdx.x * 32;
    int kc = blockIdx.y;

    #pragma unroll
    for (int u = 0; u < 8; ++u) {
        int q = u * 128 + t;
        int row = q >> 5, c4 = q & 31;
        float4 xv = *reinterpret_cast<const float4*>(
            X + (size_t)(m0 + row) * IN_DIM + kc * KC + c4 * 4);
        ushort4 hv, lv;
        hv.x = f2bf(xv.x); lv.x = f2bf(xv.x - bf2f(hv.x));
        hv.y = f2bf(xv.y); lv.y = f2bf(xv.y - bf2f(hv.y));
        hv.z = f2bf(xv.z); lv.z = f2bf(xv.z - bf2f(hv.z));
        hv.w = f2bf(xv.w); lv.w = f2bf(xv.w - bf2f(hv.w));
        *reinterpret_cast<ushort4*>(&XhiS[row][c4 * 4]) = hv;
        *reinterpret_cast<ushort4*>(&XloS[row][c4 * 4]) = lv;
    }
    #pragma unroll
    for (int u = 0; u < 16; ++u) {
        int q = u * 128 + t;
        int n = q >> 4, ck = q & 15;
        *reinterpret_cast<uint4*>(&WS[n][ck * 8]) =
            *reinterpret_cast<const uint4*>(Wt_hi + (size_t)n * IN_DIM + kc * KC + ck * 8);
    }
    __syncthreads();

    int w = t >> 6, lane = t & 63;
    int nr = lane & 15, g = lane >> 4;
    int arow = w * 16 + nr;

    bf16x8 ah[4], al[4];
    #pragma unroll
    for (int s = 0; s < 4; ++s) {
        ah[s] = *reinterpret_cast<const bf16x8*>(&XhiS[arow][s * 32 + g * 8]);
        al[s] = *reinterpret_cast<const bf16x8*>(&XloS[arow][s * 32 + g * 8]);
    }

    f32x4 acc[8] = {};

    #pragma unroll
    for (int s = 0; s < 4; ++s)
        #pragma unroll
        for (int nf = 0; nf < 8; ++nf) {
            bf16x8 bb = *reinterpret_cast<const bf16x8*>(&WS[nf * 16 + nr][s * 32 + g * 8]);
            acc[nf] = __builtin_amdgcn_mfma_f32_16x16x32_bf16(ah[s], bb, acc[nf], 0, 0, 0);
            acc[nf] = __builtin_amdgcn_mfma_f32_16x16x32_bf16(al[s], bb, acc[nf], 0, 0, 0);
        }
    __syncthreads();
    #pragma unroll
    for (int u = 0; u < 16; ++u) {
        int q = u * 128 + t;
        int n = q >> 4, ck = q & 15;
        *reinterpret_cast<uint4*>(&WS[n][ck * 8]) =
            *reinterpret_cast<const uint4*>(Wt_lo + (size_t)n * IN_DIM + kc * KC + ck * 8);
    }
    __syncthreads();
    #pragma unroll
    for (int s = 0; s < 4; ++s)
        #pragma unroll
        for (int nf = 0; nf < 8; ++nf) {
            bf16x8 bb = *reinterpret_cast<const bf16x8*>(&WS[nf * 16 + nr][s * 32 + g * 8]);
            acc[nf] = __builtin_amdgcn_mfma_f32_16x16x32_bf16(ah[s], bb, acc[nf], 0, 0, 0);
        }

    float* part = partials + (size_t)kc * NN * HID;
    #pragma unroll
    for (int nf = 0; nf < 8; ++nf)
        #pragma unroll
        for (int r = 0; r < 4; ++r)
            part[(size_t)(m0 + w * 16 + g * 4 + r) * HID + nf * 16 + nr] = acc[nf][r];
}

// ---------------------------------------------------------------------------
// 3c) reduce split-K partials + bias + relu -> rf fp32, P1_0/P2_0 bf16 prescaled
__global__ void embed_reduce(const float* __restrict__ partials, const float* __restrict__ bias,
                             const float* __restrict__ d1, const float* __restrict__ d2,
                             float* __restrict__ rf, uint16_t* __restrict__ P1,
                             uint16_t* __restrict__ P2) {
    int idx = blockIdx.x * blockDim.x + threadIdx.x;
    size_t off = (size_t)idx * 4;
    int row = (int)(off >> 7);
    int col = (int)(off & 127);

    float4 s = make_float4(0.f, 0.f, 0.f, 0.f);
    #pragma unroll
    for (int kc = 0; kc < KS; ++kc) {
        float4 p = *reinterpret_cast<const float4*>(partials + (size_t)kc * NN * HID + off);
        s.x += p.x; s.y += p.y; s.z += p.z; s.w += p.w;
    }
    float4 bv = *reinterpret_cast<const float4*>(bias + col);
    float4 v;
    v.x = fmaxf(s.x + bv.x, 0.f);
    v.y = fmaxf(s.y + bv.y, 0.f);
    v.z = fmaxf(s.z + bv.z, 0.f);
    v.w = fmaxf(s.w + bv.w, 0.f);
    *reinterpret_cast<float4*>(rf + (size_t)row * RF + col) = v;

    float s1 = d1[row], s2 = d2[row];
    ushort4 q;
    q.x = f2bf(s1 * v.x); q.y = f2bf(s1 * v.y); q.z = f2bf(s1 * v.z); q.w = f2bf(s1 * v.w);
    *reinterpret_cast<ushort4*>(P1 + (size_t)row * HID + col) = q;
    q.x = f2bf(s2 * v.x); q.y = f2bf(s2 * v.y); q.z = f2bf(s2 * v.z); q.w = f2bf(s2 * v.w);
    *reinterpret_cast<ushort4*>(P2 + (size_t)row * HID + col) = q;
}

// ---------------------------------------------------------------------------
// 4a) hop-1 gather, A1+A2 fused. Wave w: row i = w>>1, mat = w&1.
//     16 lanes per neighbor, 4 neighbors/iter, uint4 (8 bf16) per lane.
__global__ __launch_bounds__(256) void gather_k1(
    const uint16_t* __restrict__ adj1, const uint16_t* __restrict__ adj2,
    const int* __restrict__ deg1p, const int* __restrict__ deg2p,
    const uint32_t* __restrict__ P10, const uint32_t* __restrict__ P20,
    const float* __restrict__ d1, const float* __restrict__ d2,
    float* __restrict__ rf, uint16_t* __restrict__ P11, uint16_t* __restrict__ P21)
{
    int gw   = (blockIdx.x * 256 + threadIdx.x) >> 6;
    int lane = threadIdx.x & 63;
    int i    = gw >> 1;
    int mat  = gw & 1;
    int nb = lane >> 4, cq = lane & 15;

    const uint16_t* adj = mat ? adj2 + (size_t)i * CAP2 : adj1 + (size_t)i * CAP1;
    int n = (mat ? deg2p : deg1p)[i];
    const uint32_t* P = mat ? P20 : P10;

    float acc[8] = {};
    #pragma unroll 4
    for (int m = 0; m < n; m += 4) {
        int j = adj[m + nb];
        uint4 u = *reinterpret_cast<const uint4*>(P + (size_t)j * 64 + cq * 4);
        acc[0] += __uint_as_float(u.x << 16);
        acc[1] += __uint_as_float(u.x & 0xffff0000u);
        acc[2] += __uint_as_float(u.y << 16);
        acc[3] += __uint_as_float(u.y & 0xffff0000u);
        acc[4] += __uint_as_float(u.z << 16);
        acc[5] += __uint_as_float(u.z & 0xffff0000u);
        acc[6] += __uint_as_float(u.w << 16);
        acc[7] += __uint_as_float(u.w & 0xffff0000u);
    }
    #pragma unroll
    for (int k = 0; k < 8; ++k) {
        acc[k] += __shfl_xor(acc[k], 16);
        acc[k] += __shfl_xor(acc[k], 32);
    }

    if (nb == 0) {
        float di = (mat ? d2 : d1)[i];
        float o[8];
        #pragma unroll
        for (int k = 0; k < 8; ++k) o[k] = di * acc[k];

        float* dst = rf + (size_t)i * RF + 128 + mat * 128 + cq * 8;
        *reinterpret_cast<float4*>(dst)     = make_float4(o[0], o[1], o[2], o[3]);
        *reinterpret_cast<float4*>(dst + 4) = make_float4(o[4], o[5], o[6], o[7]);

        float s1 = d1[i], s2 = d2[i];
        uint32_t* q1 = reinterpret_cast<uint32_t*>(P11) + (size_t)i * 128 + mat * 64 + cq * 4;
        uint32_t* q2 = reinterpret_cast<uint32_t*>(P21) + (size_t)i * 128 + mat * 64 + cq * 4;
        uint4 v1, v2;
        v1.x = packbf(s1 * o[0], s1 * o[1]); v1.y = packbf(s1 * o[2], s1 * o[3]);
        v1.z = packbf(s1 * o[4], s1 * o[5]); v1.w = packbf(s1 * o[6], s1 * o[7]);
        v2.x = packbf(s2 * o[0], s2 * o[1]); v2.y = packbf(s2 * o[2], s2 * o[3]);
        v2.z = packbf(s2 * o[4], s2 * o[5]); v2.w = packbf(s2 * o[6], s2 * o[7]);
        *reinterpret_cast<uint4*>(q1) = v1;
        *reinterpret_cast<uint4*>(q2) = v2;
    }
}

// ---------------------------------------------------------------------------
// 4b) hop-2 gather. Wave w: row i = w>>2, mat = (w>>1)&1, half = w&1.
__global__ __launch_bounds__(256) void gather_k2(
    const uint16_t* __restrict__ adj1, const uint16_t* __restrict__ adj2,
    const int* __restrict__ deg1p, const int* __restrict__ deg2p,
    const uint32_t* __restrict__ P11, const uint32_t* __restrict__ P21,
    const float* __restrict__ d1, const float* __restrict__ d2,
    float* __restrict__ rf)
{
    int gw   = (blockIdx.x * 256 + threadIdx.x) >> 6;
    int lane = threadIdx.x & 63;
    int i    = gw >> 2;
    int mat  = (gw >> 1) & 1;
    int half = gw & 1;
    int nb = lane >> 4, cq = lane & 15;

    const uint16_t* adj = mat ? adj2 + (size_t)i * CAP2 : adj1 + (size_t)i * CAP1;
    int n = (mat ? deg2p : deg1p)[i];
    const uint32_t* P = mat ? P21 : P11;

    float acc[8] = {};
    #pragma unroll 4
    for (int m = 0; m < n; m += 4) {
        int j = adj[m + nb];
        uint4 u = *reinterpret_cast<const uint4*>(P + (size_t)j * 128 + half * 64 + cq * 4);
        acc[0] += __uint_as_float(u.x << 16);
        acc[1] += __uint_as_float(u.x & 0xffff0000u);
        acc[2] += __uint_as_float(u.y << 16);
        acc[3] += __uint_as_float(u.y & 0xffff0000u);
        acc[4] += __uint_as_float(u.z << 16);
        acc[5] += __uint_as_float(u.z & 0xffff0000u);
        acc[6] += __uint_as_float(u.w << 16);
        acc[7] += __uint_as_float(u.w & 0xffff0000u);
    }
    #pragma unroll
    for (int k = 0; k < 8; ++k) {
        acc[k] += __shfl_xor(acc[k], 16);
        acc[k] += __shfl_xor(acc[k], 32);
    }

    if (nb == 0) {
        float di = (mat ? d2 : d1)[i];
        float* dst = rf + (size_t)i * RF + 384 + mat * 256 + half * 128 + cq * 8;
        *reinterpret_cast<float4*>(dst) =
            make_float4(di * acc[0], di * acc[1], di * acc[2], di * acc[3]);
        *reinterpret_cast<float4*>(dst + 4) =
            make_float4(di * acc[4], di * acc[5], di * acc[6], di * acc[7]);
    }
}

// ---------------------------------------------------------------------------
// 5) classifier GEMM: out = rf @ Wc + bc   [4096,896]@[896,10]
__global__ void cls_gemm(const float* __restrict__ rf, const float* __restrict__ Wc,
                         const float* __restrict__ bc, float* __restrict__ out) {
    int wave = threadIdx.x >> 6;
    int lane = threadIdx.x & 63;
    int row  = blockIdx.x * 4 + wave;

    float acc[10] = {};
    for (int k = lane; k < RF; k += 64) {
        float x = rf[(size_t)row * RF + k];
        #pragma unroll
        for (int c = 0; c < 10; ++c) acc[c] += x * Wc[k * 10 + c];
    }
    #pragma unroll
    for (int c = 0; c < 10; ++c)
        #pragma unroll
        for (int off = 32; off; off >>= 1) acc[c] += __shfl_down(acc[c], off);

    if (lane == 0) {
        #pragma unroll
        for (int c = 0; c < 10; ++c) out[(size_t)row * 10 + c] = acc[c] + bc[c];
    }
}

// ---------------------------------------------------------------------------
extern "C" void kernel_launch(void* const* d_in, const int* in_sizes, int n_in,
                              void* d_out, int out_size, void* d_ws, size_t ws_size,
                              hipStream_t stream) {
    const float* X       = (const float*)d_in[0];
    const int*   ei      = (const int*)d_in[1];
    const float* W_embed = (const float*)d_in[2];
    const float* b_embed = (const float*)d_in[3];
    const float* W_cls   = (const float*)d_in[4];
    const float* b_cls   = (const float*)d_in[5];
    float* out = (float*)d_out;

    int nE = in_sizes[1] / 2;

    // workspace layout (all 16B-aligned)
    uint32_t* Abits = (uint32_t*)d_ws;                         // 2 MB
    float* d1 = (float*)(Abits + (size_t)NN * NW);             // 16 KB
    float* d2 = d1 + NN;                                       // 16 KB
    float* rf = d2 + NN;                                       // 14.68 MB [NN][RF]
    uint16_t* P1_0 = (uint16_t*)(rf + (size_t)NN * RF);        // [NN+1][128] bf16
    uint16_t* P2_0 = P1_0 + (size_t)(NN + 1) * HID;
    uint16_t* P1_1 = P2_0 + (size_t)(NN + 1) * HID;            // [NN+1][256] bf16
    uint16_t* P2_1 = P1_1 + (size_t)(NN + 1) * 256;
    uint16_t* Wt_hi = P2_1 + (size_t)(NN + 1) * 256;           // 256 KB
    uint16_t* Wt_lo = Wt_hi + (size_t)HID * IN_DIM;            // 256 KB
    float* partials = (float*)(Wt_lo + (size_t)HID * IN_DIM);  // 16 MB [KS][NN][128]
    uint16_t* adj1 = (uint16_t*)(partials + (size_t)KS * NN * HID); // 512 KB
    uint16_t* adj2 = adj1 + (size_t)NN * CAP1;                 // 8 MB
    int* deg1p = (int*)(adj2 + (size_t)NN * CAP2);             // 16 KB
    int* deg2p = deg1p + NN;                                   // 16 KB

    hipMemsetAsync(Abits, 0, (size_t)NN * NW * sizeof(uint32_t), stream);

    scatter_edges<<<(nE + 255) / 256, 256, 0, stream>>>(ei, Abits, nE);
    zero_pads<<<1, 256, 0, stream>>>((uint32_t*)P1_0, (uint32_t*)P2_0,
                                     (uint32_t*)P1_1, (uint32_t*)P2_1);
    twohop<<<NN, 128, 0, stream>>>(Abits, adj1, adj2, deg1p, deg2p, d1, d2);

    convert_w<<<IN_DIM / 8, HID, 0, stream>>>(W_embed, Wt_hi, Wt_lo);
    embed_mfma<<<dim3(NN / 32, KS), 128, 0, stream>>>(X, Wt_hi, Wt_lo, partials);
    embed_reduce<<<(NN * HID / 4) / 256, 256, 0, stream>>>(partials, b_embed, d1, d2,
                                                           rf, P1_0, P2_0);

    gather_k1<<<NN * 2 * 64 / 256, 256, 0, stream>>>(
        adj1, adj2, deg1p, deg2p,
        (const uint32_t*)P1_0, (const uint32_t*)P2_0, d1, d2,
        rf, P1_1, P2_1);
    gather_k2<<<NN * 4 * 64 / 256, 256, 0, stream>>>(
        adj1, adj2, deg1p, deg2p,
        (const uint32_t*)P1_1, (const uint32_t*)P2_1, d1, d2, rf);

    cls_gemm<<<NN / 4, 256, 0, stream>>>(rf, W_cls, b_cls, out);
}

// Round 5
// 120.761 us; speedup vs baseline: 1.6623x; 1.0150x over previous
//
#include <hip/hip_runtime.h>
#include <hip/hip_bf16.h>
#include <stdint.h>

// Problem constants (match reference)
#define NN      4096
#define IN_DIM  1024
#define HID     128
#define RF      896          // (2^(K+1)-1)*HID
#define NW      128          // words per bitmask row (4096/32)
#define CAP1    64           // adj1 stride (1-hop deg ~16, max ~40)
#define CAP2    1024         // adj2 stride (2-hop deg ~240, max ~600)
#define KS      8            // split-K chunks for embed gemm
#define KC      (IN_DIM/KS)  // 128

typedef __attribute__((ext_vector_type(8))) short   bf16x8;
typedef __attribute__((ext_vector_type(4))) float   f32x4;

static __device__ __forceinline__ uint16_t f2bf(float f) {
    __hip_bfloat16 h = __float2bfloat16(f);   // RNE
    return *reinterpret_cast<uint16_t*>(&h);
}
static __device__ __forceinline__ float bf2f(uint16_t u) {
    __hip_bfloat16 h = *reinterpret_cast<__hip_bfloat16*>(&u);
    return __bfloat162float(h);
}
static __device__ __forceinline__ uint32_t packbf(float lo, float hi) {
    return (uint32_t)f2bf(lo) | ((uint32_t)f2bf(hi) << 16);
}

// ---------------------------------------------------------------------------
// 0) zero_init: replaces hipMemsetAsync (rocclr fillBuffer cost 40 us!) and
//    zero_pads. Blocks 0..511 zero Abits (2 MB); block 512 zeros P pad rows.
__global__ __launch_bounds__(256) void zero_init(
    uint32_t* __restrict__ Abits, uint32_t* __restrict__ p10, uint32_t* __restrict__ p20,
    uint32_t* __restrict__ p11, uint32_t* __restrict__ p21)
{
    int b = blockIdx.x, t = threadIdx.x;
    if (b < 512) {
        uint4* p = reinterpret_cast<uint4*>(Abits);
        p[b * 256 + t] = make_uint4(0, 0, 0, 0);
    } else {
        if (t < 64)  { p10[(size_t)NN * 64 + t] = 0;  p20[(size_t)NN * 64 + t] = 0; }
        if (t < 128) { p11[(size_t)NN * 128 + t] = 0; p21[(size_t)NN * 128 + t] = 0; }
    }
}

// ---------------------------------------------------------------------------
// 1) scatter edges into bitmask adjacency  A[src][dst] = 1
__global__ void scatter_edges(const int* __restrict__ ei, uint32_t* __restrict__ Abits, int nE) {
    int e = blockIdx.x * blockDim.x + threadIdx.x;
    if (e < nE) {
        int s = ei[e];
        int d = ei[nE + e];
        atomicOr(&Abits[(size_t)s * NW + (d >> 5)], 1u << (d & 31));
    }
}

// ---------------------------------------------------------------------------
// 2) 2-hop path counts -> CSR adjacency lists (padded to x4 with sentinel NN)
//    + d1,d2 = rsqrt(deg+1e-8).  One block (128 thr) per row i.
__global__ void twohop(const uint32_t* __restrict__ Abits,
                       uint16_t* __restrict__ adj1, uint16_t* __restrict__ adj2,
                       int* __restrict__ deg1p, int* __restrict__ deg2p,
                       float* __restrict__ d1, float* __restrict__ d2) {
    __shared__ uint16_t cnt[NN];       // 8 KB
    __shared__ uint32_t rowbits[NW];   // 512 B
    __shared__ int wtot[2][2];

    int i = blockIdx.x;
    int t = threadIdx.x;  // 0..127
    int lane = t & 63, wv = t >> 6;

    for (int j = t; j < NN; j += 128) cnt[j] = 0;
    rowbits[t] = Abits[(size_t)i * NW + t];
    __syncthreads();

    for (int w = 0; w < NW; ++w) {
        uint32_t bits = rowbits[w];
        while (bits) {
            int b = __ffs(bits) - 1;
            bits &= bits - 1;
            int k = w * 32 + b;
            uint32_t kw = Abits[(size_t)k * NW + t];
            while (kw) {
                int bb = __ffs(kw) - 1;
                kw &= kw - 1;
                cnt[t * 32 + bb]++;
            }
        }
    }
    __syncthreads();

    uint32_t self = rowbits[t];
    uint32_t m2 = 0;
    #pragma unroll
    for (int b = 0; b < 32; ++b) {
        int j = t * 32 + b;
        int c = (int)cnt[j] - (int)((self >> b) & 1u) - (j == i ? 1 : 0);
        if (c > 0) m2 |= (1u << b);
    }

    int pc1 = __popc(self), pc2 = __popc(m2);
    int x1 = pc1, x2 = pc2;
    #pragma unroll
    for (int off = 1; off < 64; off <<= 1) {
        int y1 = __shfl_up(x1, off), y2 = __shfl_up(x2, off);
        if (lane >= off) { x1 += y1; x2 += y2; }
    }
    if (lane == 63) { wtot[wv][0] = x1; wtot[wv][1] = x2; }
    __syncthreads();

    int b1 = (wv ? wtot[0][0] : 0) + x1 - pc1;   // exclusive prefix
    int b2 = (wv ? wtot[0][1] : 0) + x2 - pc2;

    uint32_t b = self; int o = b1;
    while (b) { int bb = __ffs(b) - 1; b &= b - 1; adj1[(size_t)i * CAP1 + o++] = (uint16_t)(t * 32 + bb); }
    b = m2; o = b2;
    while (b) { int bb = __ffs(b) - 1; b &= b - 1; adj2[(size_t)i * CAP2 + o++] = (uint16_t)(t * 32 + bb); }

    if (t == 0) {
        int tot1 = wtot[0][0] + wtot[1][0];
        int tot2 = wtot[0][1] + wtot[1][1];
        int n1 = (tot1 + 3) & ~3, n2 = (tot2 + 3) & ~3;
        for (int z = tot1; z < n1; ++z) adj1[(size_t)i * CAP1 + z] = (uint16_t)NN;
        for (int z = tot2; z < n2; ++z) adj2[(size_t)i * CAP2 + z] = (uint16_t)NN;
        deg1p[i] = n1; deg2p[i] = n2;
        d1[i] = rsqrtf((float)tot1 + 1e-8f);
        d2[i] = rsqrtf((float)tot2 + 1e-8f);
    }
}

// ---------------------------------------------------------------------------
// 3a) convert W -> transposed bf16 hi/lo
__global__ void convert_w(const float* __restrict__ W,
                          uint16_t* __restrict__ Wt_hi, uint16_t* __restrict__ Wt_lo) {
    int n  = threadIdx.x;
    int k0 = blockIdx.x * 8;
    uint16_t h[8], l[8];
    #pragma unroll
    for (int j = 0; j < 8; ++j) {
        float x = W[(size_t)(k0 + j) * HID + n];
        h[j] = f2bf(x);
        l[j] = f2bf(x - bf2f(h[j]));
    }
    ushort4* ph = reinterpret_cast<ushort4*>(Wt_hi + (size_t)n * IN_DIM + k0);
    ushort4* pl = reinterpret_cast<ushort4*>(Wt_lo + (size_t)n * IN_DIM + k0);
    ph[0] = make_ushort4(h[0], h[1], h[2], h[3]);
    ph[1] = make_ushort4(h[4], h[5], h[6], h[7]);
    pl[0] = make_ushort4(l[0], l[1], l[2], l[3]);
    pl[1] = make_ushort4(l[4], l[5], l[6], l[7]);
}

// ---------------------------------------------------------------------------
// 3b) embed MFMA GEMM, bf16x2 split, split-K
#define XSTR 136
__global__ __launch_bounds__(128) void embed_mfma(
    const float* __restrict__ X, const uint16_t* __restrict__ Wt_hi,
    const uint16_t* __restrict__ Wt_lo, float* __restrict__ partials)
{
    __shared__ uint16_t XhiS[32][XSTR];
    __shared__ uint16_t XloS[32][XSTR];
    __shared__ uint16_t WS[128][XSTR];

    int t  = threadIdx.x;
    int m0 = blockIdx.x * 32;
    int kc = blockIdx.y;

    #pragma unroll
    for (int u = 0; u < 8; ++u) {
        int q = u * 128 + t;
        int row = q >> 5, c4 = q & 31;
        float4 xv = *reinterpret_cast<const float4*>(
            X + (size_t)(m0 + row) * IN_DIM + kc * KC + c4 * 4);
        ushort4 hv, lv;
        hv.x = f2bf(xv.x); lv.x = f2bf(xv.x - bf2f(hv.x));
        hv.y = f2bf(xv.y); lv.y = f2bf(xv.y - bf2f(hv.y));
        hv.z = f2bf(xv.z); lv.z = f2bf(xv.z - bf2f(hv.z));
        hv.w = f2bf(xv.w); lv.w = f2bf(xv.w - bf2f(hv.w));
        *reinterpret_cast<ushort4*>(&XhiS[row][c4 * 4]) = hv;
        *reinterpret_cast<ushort4*>(&XloS[row][c4 * 4]) = lv;
    }
    #pragma unroll
    for (int u = 0; u < 16; ++u) {
        int q = u * 128 + t;
        int n = q >> 4, ck = q & 15;
        *reinterpret_cast<uint4*>(&WS[n][ck * 8]) =
            *reinterpret_cast<const uint4*>(Wt_hi + (size_t)n * IN_DIM + kc * KC + ck * 8);
    }
    __syncthreads();

    int w = t >> 6, lane = t & 63;
    int nr = lane & 15, g = lane >> 4;
    int arow = w * 16 + nr;

    bf16x8 ah[4], al[4];
    #pragma unroll
    for (int s = 0; s < 4; ++s) {
        ah[s] = *reinterpret_cast<const bf16x8*>(&XhiS[arow][s * 32 + g * 8]);
        al[s] = *reinterpret_cast<const bf16x8*>(&XloS[arow][s * 32 + g * 8]);
    }

    f32x4 acc[8] = {};

    #pragma unroll
    for (int s = 0; s < 4; ++s)
        #pragma unroll
        for (int nf = 0; nf < 8; ++nf) {
            bf16x8 bb = *reinterpret_cast<const bf16x8*>(&WS[nf * 16 + nr][s * 32 + g * 8]);
            acc[nf] = __builtin_amdgcn_mfma_f32_16x16x32_bf16(ah[s], bb, acc[nf], 0, 0, 0);
            acc[nf] = __builtin_amdgcn_mfma_f32_16x16x32_bf16(al[s], bb, acc[nf], 0, 0, 0);
        }
    __syncthreads();
    #pragma unroll
    for (int u = 0; u < 16; ++u) {
        int q = u * 128 + t;
        int n = q >> 4, ck = q & 15;
        *reinterpret_cast<uint4*>(&WS[n][ck * 8]) =
            *reinterpret_cast<const uint4*>(Wt_lo + (size_t)n * IN_DIM + kc * KC + ck * 8);
    }
    __syncthreads();
    #pragma unroll
    for (int s = 0; s < 4; ++s)
        #pragma unroll
        for (int nf = 0; nf < 8; ++nf) {
            bf16x8 bb = *reinterpret_cast<const bf16x8*>(&WS[nf * 16 + nr][s * 32 + g * 8]);
            acc[nf] = __builtin_amdgcn_mfma_f32_16x16x32_bf16(ah[s], bb, acc[nf], 0, 0, 0);
        }

    float* part = partials + (size_t)kc * NN * HID;
    #pragma unroll
    for (int nf = 0; nf < 8; ++nf)
        #pragma unroll
        for (int r = 0; r < 4; ++r)
            part[(size_t)(m0 + w * 16 + g * 4 + r) * HID + nf * 16 + nr] = acc[nf][r];
}

// ---------------------------------------------------------------------------
// 3c) reduce split-K partials + bias + relu -> rf fp32, P1_0/P2_0 bf16 prescaled
__global__ void embed_reduce(const float* __restrict__ partials, const float* __restrict__ bias,
                             const float* __restrict__ d1, const float* __restrict__ d2,
                             float* __restrict__ rf, uint16_t* __restrict__ P1,
                             uint16_t* __restrict__ P2) {
    int idx = blockIdx.x * blockDim.x + threadIdx.x;
    size_t off = (size_t)idx * 4;
    int row = (int)(off >> 7);
    int col = (int)(off & 127);

    float4 s = make_float4(0.f, 0.f, 0.f, 0.f);
    #pragma unroll
    for (int kc = 0; kc < KS; ++kc) {
        float4 p = *reinterpret_cast<const float4*>(partials + (size_t)kc * NN * HID + off);
        s.x += p.x; s.y += p.y; s.z += p.z; s.w += p.w;
    }
    float4 bv = *reinterpret_cast<const float4*>(bias + col);
    float4 v;
    v.x = fmaxf(s.x + bv.x, 0.f);
    v.y = fmaxf(s.y + bv.y, 0.f);
    v.z = fmaxf(s.z + bv.z, 0.f);
    v.w = fmaxf(s.w + bv.w, 0.f);
    *reinterpret_cast<float4*>(rf + (size_t)row * RF + col) = v;

    float s1 = d1[row], s2 = d2[row];
    ushort4 q;
    q.x = f2bf(s1 * v.x); q.y = f2bf(s1 * v.y); q.z = f2bf(s1 * v.z); q.w = f2bf(s1 * v.w);
    *reinterpret_cast<ushort4*>(P1 + (size_t)row * HID + col) = q;
    q.x = f2bf(s2 * v.x); q.y = f2bf(s2 * v.y); q.z = f2bf(s2 * v.z); q.w = f2bf(s2 * v.w);
    *reinterpret_cast<ushort4*>(P2 + (size_t)row * HID + col) = q;
}

// ---------------------------------------------------------------------------
// 4a) hop-1 gather, A1+A2 fused. Wave w: row i = w>>1, mat = w&1.
__global__ __launch_bounds__(256) void gather_k1(
    const uint16_t* __restrict__ adj1, const uint16_t* __restrict__ adj2,
    const int* __restrict__ deg1p, const int* __restrict__ deg2p,
    const uint32_t* __restrict__ P10, const uint32_t* __restrict__ P20,
    const float* __restrict__ d1, const float* __restrict__ d2,
    float* __restrict__ rf, uint16_t* __restrict__ P11, uint16_t* __restrict__ P21)
{
    int gw   = (blockIdx.x * 256 + threadIdx.x) >> 6;
    int lane = threadIdx.x & 63;
    int i    = gw >> 1;
    int mat  = gw & 1;
    int nb = lane >> 4, cq = lane & 15;

    const uint16_t* adj = mat ? adj2 + (size_t)i * CAP2 : adj1 + (size_t)i * CAP1;
    int n = (mat ? deg2p : deg1p)[i];
    const uint32_t* P = mat ? P20 : P10;

    float acc[8] = {};
    #pragma unroll 4
    for (int m = 0; m < n; m += 4) {
        int j = adj[m + nb];
        uint4 u = *reinterpret_cast<const uint4*>(P + (size_t)j * 64 + cq * 4);
        acc[0] += __uint_as_float(u.x << 16);
        acc[1] += __uint_as_float(u.x & 0xffff0000u);
        acc[2] += __uint_as_float(u.y << 16);
        acc[3] += __uint_as_float(u.y & 0xffff0000u);
        acc[4] += __uint_as_float(u.z << 16);
        acc[5] += __uint_as_float(u.z & 0xffff0000u);
        acc[6] += __uint_as_float(u.w << 16);
        acc[7] += __uint_as_float(u.w & 0xffff0000u);
    }
    #pragma unroll
    for (int k = 0; k < 8; ++k) {
        acc[k] += __shfl_xor(acc[k], 16);
        acc[k] += __shfl_xor(acc[k], 32);
    }

    if (nb == 0) {
        float di = (mat ? d2 : d1)[i];
        float o[8];
        #pragma unroll
        for (int k = 0; k < 8; ++k) o[k] = di * acc[k];

        float* dst = rf + (size_t)i * RF + 128 + mat * 128 + cq * 8;
        *reinterpret_cast<float4*>(dst)     = make_float4(o[0], o[1], o[2], o[3]);
        *reinterpret_cast<float4*>(dst + 4) = make_float4(o[4], o[5], o[6], o[7]);

        float s1 = d1[i], s2 = d2[i];
        uint32_t* q1 = reinterpret_cast<uint32_t*>(P11) + (size_t)i * 128 + mat * 64 + cq * 4;
        uint32_t* q2 = reinterpret_cast<uint32_t*>(P21) + (size_t)i * 128 + mat * 64 + cq * 4;
        uint4 v1, v2;
        v1.x = packbf(s1 * o[0], s1 * o[1]); v1.y = packbf(s1 * o[2], s1 * o[3]);
        v1.z = packbf(s1 * o[4], s1 * o[5]); v1.w = packbf(s1 * o[6], s1 * o[7]);
        v2.x = packbf(s2 * o[0], s2 * o[1]); v2.y = packbf(s2 * o[2], s2 * o[3]);
        v2.z = packbf(s2 * o[4], s2 * o[5]); v2.w = packbf(s2 * o[6], s2 * o[7]);
        *reinterpret_cast<uint4*>(q1) = v1;
        *reinterpret_cast<uint4*>(q2) = v2;
    }
}

// ---------------------------------------------------------------------------
// 4b) hop-2 gather. Wave w: row i = w>>2, mat = (w>>1)&1, half = w&1.
__global__ __launch_bounds__(256) void gather_k2(
    const uint16_t* __restrict__ adj1, const uint16_t* __restrict__ adj2,
    const int* __restrict__ deg1p, const int* __restrict__ deg2p,
    const uint32_t* __restrict__ P11, const uint32_t* __restrict__ P21,
    const float* __restrict__ d1, const float* __restrict__ d2,
    float* __restrict__ rf)
{
    int gw   = (blockIdx.x * 256 + threadIdx.x) >> 6;
    int lane = threadIdx.x & 63;
    int i    = gw >> 2;
    int mat  = (gw >> 1) & 1;
    int half = gw & 1;
    int nb = lane >> 4, cq = lane & 15;

    const uint16_t* adj = mat ? adj2 + (size_t)i * CAP2 : adj1 + (size_t)i * CAP1;
    int n = (mat ? deg2p : deg1p)[i];
    const uint32_t* P = mat ? P21 : P11;

    float acc[8] = {};
    #pragma unroll 4
    for (int m = 0; m < n; m += 4) {
        int j = adj[m + nb];
        uint4 u = *reinterpret_cast<const uint4*>(P + (size_t)j * 128 + half * 64 + cq * 4);
        acc[0] += __uint_as_float(u.x << 16);
        acc[1] += __uint_as_float(u.x & 0xffff0000u);
        acc[2] += __uint_as_float(u.y << 16);
        acc[3] += __uint_as_float(u.y & 0xffff0000u);
        acc[4] += __uint_as_float(u.z << 16);
        acc[5] += __uint_as_float(u.z & 0xffff0000u);
        acc[6] += __uint_as_float(u.w << 16);
        acc[7] += __uint_as_float(u.w & 0xffff0000u);
    }
    #pragma unroll
    for (int k = 0; k < 8; ++k) {
        acc[k] += __shfl_xor(acc[k], 16);
        acc[k] += __shfl_xor(acc[k], 32);
    }

    if (nb == 0) {
        float di = (mat ? d2 : d1)[i];
        float* dst = rf + (size_t)i * RF + 384 + mat * 256 + half * 128 + cq * 8;
        *reinterpret_cast<float4*>(dst) =
            make_float4(di * acc[0], di * acc[1], di * acc[2], di * acc[3]);
        *reinterpret_cast<float4*>(dst + 4) =
            make_float4(di * acc[4], di * acc[5], di * acc[6], di * acc[7]);
    }
}

// ---------------------------------------------------------------------------
// 5) classifier GEMM: out = rf @ Wc + bc   [4096,896]@[896,10]
__global__ void cls_gemm(const float* __restrict__ rf, const float* __restrict__ Wc,
                         const float* __restrict__ bc, float* __restrict__ out) {
    int wave = threadIdx.x >> 6;
    int lane = threadIdx.x & 63;
    int row  = blockIdx.x * 4 + wave;

    float acc[10] = {};
    for (int k = lane; k < RF; k += 64) {
        float x = rf[(size_t)row * RF + k];
        #pragma unroll
        for (int c = 0; c < 10; ++c) acc[c] += x * Wc[k * 10 + c];
    }
    #pragma unroll
    for (int c = 0; c < 10; ++c)
        #pragma unroll
        for (int off = 32; off; off >>= 1) acc[c] += __shfl_down(acc[c], off);

    if (lane == 0) {
        #pragma unroll
        for (int c = 0; c < 10; ++c) out[(size_t)row * 10 + c] = acc[c] + bc[c];
    }
}

// ---------------------------------------------------------------------------
extern "C" void kernel_launch(void* const* d_in, const int* in_sizes, int n_in,
                              void* d_out, int out_size, void* d_ws, size_t ws_size,
                              hipStream_t stream) {
    const float* X       = (const float*)d_in[0];
    const int*   ei      = (const int*)d_in[1];
    const float* W_embed = (const float*)d_in[2];
    const float* b_embed = (const float*)d_in[3];
    const float* W_cls   = (const float*)d_in[4];
    const float* b_cls   = (const float*)d_in[5];
    float* out = (float*)d_out;

    int nE = in_sizes[1] / 2;

    // workspace layout (all 16B-aligned)
    uint32_t* Abits = (uint32_t*)d_ws;                         // 2 MB
    float* d1 = (float*)(Abits + (size_t)NN * NW);             // 16 KB
    float* d2 = d1 + NN;                                       // 16 KB
    float* rf = d2 + NN;                                       // 14.68 MB [NN][RF]
    uint16_t* P1_0 = (uint16_t*)(rf + (size_t)NN * RF);        // [NN+1][128] bf16
    uint16_t* P2_0 = P1_0 + (size_t)(NN + 1) * HID;
    uint16_t* P1_1 = P2_0 + (size_t)(NN + 1) * HID;            // [NN+1][256] bf16
    uint16_t* P2_1 = P1_1 + (size_t)(NN + 1) * 256;
    uint16_t* Wt_hi = P2_1 + (size_t)(NN + 1) * 256;           // 256 KB
    uint16_t* Wt_lo = Wt_hi + (size_t)HID * IN_DIM;            // 256 KB
    float* partials = (float*)(Wt_lo + (size_t)HID * IN_DIM);  // 16 MB [KS][NN][128]
    uint16_t* adj1 = (uint16_t*)(partials + (size_t)KS * NN * HID); // 512 KB
    uint16_t* adj2 = adj1 + (size_t)NN * CAP1;                 // 8 MB
    int* deg1p = (int*)(adj2 + (size_t)NN * CAP2);             // 16 KB
    int* deg2p = deg1p + NN;                                   // 16 KB

    zero_init<<<513, 256, 0, stream>>>(Abits, (uint32_t*)P1_0, (uint32_t*)P2_0,
                                       (uint32_t*)P1_1, (uint32_t*)P2_1);
    scatter_edges<<<(nE + 255) / 256, 256, 0, stream>>>(ei, Abits, nE);
    twohop<<<NN, 128, 0, stream>>>(Abits, adj1, adj2, deg1p, deg2p, d1, d2);

    convert_w<<<IN_DIM / 8, HID, 0, stream>>>(W_embed, Wt_hi, Wt_lo);
    embed_mfma<<<dim3(NN / 32, KS), 128, 0, stream>>>(X, Wt_hi, Wt_lo, partials);
    embed_reduce<<<(NN * HID / 4) / 256, 256, 0, stream>>>(partials, b_embed, d1, d2,
                                                           rf, P1_0, P2_0);

    gather_k1<<<NN * 2 * 64 / 256, 256, 0, stream>>>(
        adj1, adj2, deg1p, deg2p,
        (const uint32_t*)P1_0, (const uint32_t*)P2_0, d1, d2,
        rf, P1_1, P2_1);
    gather_k2<<<NN * 4 * 64 / 256, 256, 0, stream>>>(
        adj1, adj2, deg1p, deg2p,
        (const uint32_t*)P1_1, (const uint32_t*)P2_1, d1, d2, rf);

    cls_gemm<<<NN / 4, 256, 0, stream>>>(rf, W_cls, b_cls, out);
}

// Round 6
// 105.376 us; speedup vs baseline: 1.9050x; 1.1460x over previous
//
#include <hip/hip_runtime.h>
#include <hip/hip_bf16.h>
#include <stdint.h>

// Problem constants (match reference)
#define NN      4096
#define IN_DIM  1024
#define HID     128
#define RF      896          // (2^(K+1)-1)*HID
#define NW      128          // words per bitmask row (4096/32)
#define CAP1    64           // adj1 stride (1-hop deg ~16, max ~40)
#define CAP2    1024         // adj2 stride (2-hop deg ~240)
#define KS      8            // split-K chunks for embed gemm
#define KC      (IN_DIM/KS)  // 128

typedef __attribute__((ext_vector_type(8))) short   bf16x8;
typedef __attribute__((ext_vector_type(4))) float   f32x4;

static __device__ __forceinline__ uint16_t f2bf(float f) {
    __hip_bfloat16 h = __float2bfloat16(f);   // RNE
    return *reinterpret_cast<uint16_t*>(&h);
}
static __device__ __forceinline__ float bf2f(uint16_t u) {
    __hip_bfloat16 h = *reinterpret_cast<__hip_bfloat16*>(&u);
    return __bfloat162float(h);
}
static __device__ __forceinline__ uint32_t packbf(float lo, float hi) {
    return (uint32_t)f2bf(lo) | ((uint32_t)f2bf(hi) << 16);
}

// ---------------------------------------------------------------------------
// 0) prep: zero Abits (blocks 0..511), zero P pad rows (block 512),
//    convert W -> transposed bf16 hi/lo (blocks 513..640, 128 thr active)
__global__ __launch_bounds__(256) void prep(
    uint32_t* __restrict__ Abits, uint32_t* __restrict__ p10, uint32_t* __restrict__ p20,
    uint32_t* __restrict__ p11, uint32_t* __restrict__ p21,
    const float* __restrict__ W, uint16_t* __restrict__ Wt_hi, uint16_t* __restrict__ Wt_lo)
{
    int b = blockIdx.x, t = threadIdx.x;
    if (b < 512) {
        reinterpret_cast<uint4*>(Abits)[b * 256 + t] = make_uint4(0, 0, 0, 0);
    } else if (b == 512) {
        if (t < 64)  { p10[(size_t)NN * 64 + t] = 0;  p20[(size_t)NN * 64 + t] = 0; }
        if (t < 128) { p11[(size_t)NN * 128 + t] = 0; p21[(size_t)NN * 128 + t] = 0; }
    } else {
        if (t < 128) {
            int n  = t;
            int k0 = (b - 513) * 8;
            uint16_t h[8], l[8];
            #pragma unroll
            for (int j = 0; j < 8; ++j) {
                float x = W[(size_t)(k0 + j) * HID + n];
                h[j] = f2bf(x);
                l[j] = f2bf(x - bf2f(h[j]));
            }
            ushort4* ph = reinterpret_cast<ushort4*>(Wt_hi + (size_t)n * IN_DIM + k0);
            ushort4* pl = reinterpret_cast<ushort4*>(Wt_lo + (size_t)n * IN_DIM + k0);
            ph[0] = make_ushort4(h[0], h[1], h[2], h[3]);
            ph[1] = make_ushort4(h[4], h[5], h[6], h[7]);
            pl[0] = make_ushort4(l[0], l[1], l[2], l[3]);
            pl[1] = make_ushort4(l[4], l[5], l[6], l[7]);
        }
    }
}

// ---------------------------------------------------------------------------
// 1) scatter edges into bitmask adjacency  A[src][dst] = 1
__global__ void scatter_edges(const int* __restrict__ ei, uint32_t* __restrict__ Abits, int nE) {
    int e = blockIdx.x * blockDim.x + threadIdx.x;
    if (e < nE) {
        int s = ei[e];
        int d = ei[nE + e];
        atomicOr(&Abits[(size_t)s * NW + (d >> 5)], 1u << (d & 31));
    }
}

// ---------------------------------------------------------------------------
// 2) twohop2: bit-sliced threshold counters, wave-per-row (4 waves/block).
//    Lane owns words 2l,2l+1. s1/s2/s3 = (pathcount >= 1/2/3) per bit.
//    A2 = (s1&~a&~e) | (s2&(a^e)) | (s3&(a&e)),  a=A[i] bit, e=(j==i) bit.
//    Emits padded adj1/adj2 lists (sentinel NN), padded degs, d1/d2.
#define UPD(v) { s3x |= s2x & (v).x; s2x |= s1x & (v).x; s1x |= (v).x; \
                 s3y |= s2y & (v).y; s2y |= s1y & (v).y; s1y |= (v).y; }
__global__ __launch_bounds__(256) void twohop2(
    const uint32_t* __restrict__ Abits,
    uint16_t* __restrict__ adj1, uint16_t* __restrict__ adj2,
    int* __restrict__ deg1p, int* __restrict__ deg2p,
    float* __restrict__ d1, float* __restrict__ d2)
{
    __shared__ uint16_t l1s[4][CAP1];

    int wv = threadIdx.x >> 6, lane = threadIdx.x & 63;
    int i = blockIdx.x * 4 + wv;

    uint2 sv = *reinterpret_cast<const uint2*>(&Abits[(size_t)i * NW + lane * 2]);

    // ---- adj1: scan + emit
    int pc1 = __popc(sv.x) + __popc(sv.y);
    int x1 = pc1;
    #pragma unroll
    for (int off = 1; off < 64; off <<= 1) {
        int y = __shfl_up(x1, off);
        if (lane >= off) x1 += y;
    }
    int tot1 = __shfl(x1, 63);
    int o = x1 - pc1;                       // exclusive prefix
    {
        uint32_t b = sv.x;
        while (b) { int bb = __ffs(b) - 1; b &= b - 1;
                    uint16_t v = (uint16_t)(lane * 64 + bb);
                    l1s[wv][o] = v; adj1[(size_t)i * CAP1 + o] = v; ++o; }
        b = sv.y;
        while (b) { int bb = __ffs(b) - 1; b &= b - 1;
                    uint16_t v = (uint16_t)(lane * 64 + 32 + bb);
                    l1s[wv][o] = v; adj1[(size_t)i * CAP1 + o] = v; ++o; }
    }
    int n1 = (tot1 + 3) & ~3;
    if (lane == 0) {
        for (int z = tot1; z < n1; ++z) adj1[(size_t)i * CAP1 + z] = (uint16_t)NN;
        deg1p[i] = n1;
        d1[i] = rsqrtf((float)tot1 + 1e-8f);
    }
    __syncthreads();

    // ---- path-count thresholds over neighbors
    uint32_t s1x = 0, s2x = 0, s3x = 0, s1y = 0, s2y = 0, s3y = 0;
    int m = 0;
    for (; m + 4 <= tot1; m += 4) {
        int k0 = l1s[wv][m], k1 = l1s[wv][m + 1], k2 = l1s[wv][m + 2], k3 = l1s[wv][m + 3];
        uint2 a = *reinterpret_cast<const uint2*>(&Abits[(size_t)k0 * NW + lane * 2]);
        uint2 b = *reinterpret_cast<const uint2*>(&Abits[(size_t)k1 * NW + lane * 2]);
        uint2 c = *reinterpret_cast<const uint2*>(&Abits[(size_t)k2 * NW + lane * 2]);
        uint2 d = *reinterpret_cast<const uint2*>(&Abits[(size_t)k3 * NW + lane * 2]);
        UPD(a); UPD(b); UPD(c); UPD(d);
    }
    for (; m < tot1; ++m) {
        int k = l1s[wv][m];
        uint2 a = *reinterpret_cast<const uint2*>(&Abits[(size_t)k * NW + lane * 2]);
        UPD(a);
    }

    uint32_t iwx = ((i >> 5) == lane * 2)     ? (1u << (i & 31)) : 0u;
    uint32_t iwy = ((i >> 5) == lane * 2 + 1) ? (1u << (i & 31)) : 0u;
    uint32_t a2x = (s1x & ~sv.x & ~iwx) | (s2x & (sv.x ^ iwx)) | (s3x & (sv.x & iwx));
    uint32_t a2y = (s1y & ~sv.y & ~iwy) | (s2y & (sv.y ^ iwy)) | (s3y & (sv.y & iwy));

    // ---- adj2: scan + emit
    int pc2 = __popc(a2x) + __popc(a2y);
    int x2 = pc2;
    #pragma unroll
    for (int off = 1; off < 64; off <<= 1) {
        int y = __shfl_up(x2, off);
        if (lane >= off) x2 += y;
    }
    int tot2 = __shfl(x2, 63);
    o = x2 - pc2;
    {
        uint32_t b = a2x;
        while (b) { int bb = __ffs(b) - 1; b &= b - 1;
                    adj2[(size_t)i * CAP2 + o] = (uint16_t)(lane * 64 + bb); ++o; }
        b = a2y;
        while (b) { int bb = __ffs(b) - 1; b &= b - 1;
                    adj2[(size_t)i * CAP2 + o] = (uint16_t)(lane * 64 + 32 + bb); ++o; }
    }
    int n2 = (tot2 + 3) & ~3;
    if (lane == 0) {
        for (int z = tot2; z < n2; ++z) adj2[(size_t)i * CAP2 + z] = (uint16_t)NN;
        deg2p[i] = n2;
        d2[i] = rsqrtf((float)tot2 + 1e-8f);
    }
}

// ---------------------------------------------------------------------------
// 3b) embed MFMA GEMM, bf16x2 split, split-K
#define XSTR 136
__global__ __launch_bounds__(128) void embed_mfma(
    const float* __restrict__ X, const uint16_t* __restrict__ Wt_hi,
    const uint16_t* __restrict__ Wt_lo, float* __restrict__ partials)
{
    __shared__ uint16_t XhiS[32][XSTR];
    __shared__ uint16_t XloS[32][XSTR];
    __shared__ uint16_t WS[128][XSTR];

    int t  = threadIdx.x;
    int m0 = blockIdx.x * 32;
    int kc = blockIdx.y;

    #pragma unroll
    for (int u = 0; u < 8; ++u) {
        int q = u * 128 + t;
        int row = q >> 5, c4 = q & 31;
        float4 xv = *reinterpret_cast<const float4*>(
            X + (size_t)(m0 + row) * IN_DIM + kc * KC + c4 * 4);
        ushort4 hv, lv;
        hv.x = f2bf(xv.x); lv.x = f2bf(xv.x - bf2f(hv.x));
        hv.y = f2bf(xv.y); lv.y = f2bf(xv.y - bf2f(hv.y));
        hv.z = f2bf(xv.z); lv.z = f2bf(xv.z - bf2f(hv.z));
        hv.w = f2bf(xv.w); lv.w = f2bf(xv.w - bf2f(hv.w));
        *reinterpret_cast<ushort4*>(&XhiS[row][c4 * 4]) = hv;
        *reinterpret_cast<ushort4*>(&XloS[row][c4 * 4]) = lv;
    }
    #pragma unroll
    for (int u = 0; u < 16; ++u) {
        int q = u * 128 + t;
        int n = q >> 4, ck = q & 15;
        *reinterpret_cast<uint4*>(&WS[n][ck * 8]) =
            *reinterpret_cast<const uint4*>(Wt_hi + (size_t)n * IN_DIM + kc * KC + ck * 8);
    }
    __syncthreads();

    int w = t >> 6, lane = t & 63;
    int nr = lane & 15, g = lane >> 4;
    int arow = w * 16 + nr;

    bf16x8 ah[4], al[4];
    #pragma unroll
    for (int s = 0; s < 4; ++s) {
        ah[s] = *reinterpret_cast<const bf16x8*>(&XhiS[arow][s * 32 + g * 8]);
        al[s] = *reinterpret_cast<const bf16x8*>(&XloS[arow][s * 32 + g * 8]);
    }

    f32x4 acc[8] = {};

    #pragma unroll
    for (int s = 0; s < 4; ++s)
        #pragma unroll
        for (int nf = 0; nf < 8; ++nf) {
            bf16x8 bb = *reinterpret_cast<const bf16x8*>(&WS[nf * 16 + nr][s * 32 + g * 8]);
            acc[nf] = __builtin_amdgcn_mfma_f32_16x16x32_bf16(ah[s], bb, acc[nf], 0, 0, 0);
            acc[nf] = __builtin_amdgcn_mfma_f32_16x16x32_bf16(al[s], bb, acc[nf], 0, 0, 0);
        }
    __syncthreads();
    #pragma unroll
    for (int u = 0; u < 16; ++u) {
        int q = u * 128 + t;
        int n = q >> 4, ck = q & 15;
        *reinterpret_cast<uint4*>(&WS[n][ck * 8]) =
            *reinterpret_cast<const uint4*>(Wt_lo + (size_t)n * IN_DIM + kc * KC + ck * 8);
    }
    __syncthreads();
    #pragma unroll
    for (int s = 0; s < 4; ++s)
        #pragma unroll
        for (int nf = 0; nf < 8; ++nf) {
            bf16x8 bb = *reinterpret_cast<const bf16x8*>(&WS[nf * 16 + nr][s * 32 + g * 8]);
            acc[nf] = __builtin_amdgcn_mfma_f32_16x16x32_bf16(ah[s], bb, acc[nf], 0, 0, 0);
        }

    float* part = partials + (size_t)kc * NN * HID;
    #pragma unroll
    for (int nf = 0; nf < 8; ++nf)
        #pragma unroll
        for (int r = 0; r < 4; ++r)
            part[(size_t)(m0 + w * 16 + g * 4 + r) * HID + nf * 16 + nr] = acc[nf][r];
}

// ---------------------------------------------------------------------------
// 3c) reduce split-K partials + bias + relu -> rf bf16 (cols 0:128) + P1_0/P2_0
__global__ void embed_reduce(const float* __restrict__ partials, const float* __restrict__ bias,
                             const float* __restrict__ d1, const float* __restrict__ d2,
                             uint16_t* __restrict__ rfb, uint16_t* __restrict__ P1,
                             uint16_t* __restrict__ P2) {
    int idx = blockIdx.x * blockDim.x + threadIdx.x;
    size_t off = (size_t)idx * 4;
    int row = (int)(off >> 7);
    int col = (int)(off & 127);

    float4 s = make_float4(0.f, 0.f, 0.f, 0.f);
    #pragma unroll
    for (int kc = 0; kc < KS; ++kc) {
        float4 p = *reinterpret_cast<const float4*>(partials + (size_t)kc * NN * HID + off);
        s.x += p.x; s.y += p.y; s.z += p.z; s.w += p.w;
    }
    float4 bv = *reinterpret_cast<const float4*>(bias + col);
    float4 v;
    v.x = fmaxf(s.x + bv.x, 0.f);
    v.y = fmaxf(s.y + bv.y, 0.f);
    v.z = fmaxf(s.z + bv.z, 0.f);
    v.w = fmaxf(s.w + bv.w, 0.f);

    uint2 rv;
    rv.x = packbf(v.x, v.y); rv.y = packbf(v.z, v.w);
    *reinterpret_cast<uint2*>(rfb + (size_t)row * RF + col) = rv;

    float s1 = d1[row], s2 = d2[row];
    ushort4 q;
    q.x = f2bf(s1 * v.x); q.y = f2bf(s1 * v.y); q.z = f2bf(s1 * v.z); q.w = f2bf(s1 * v.w);
    *reinterpret_cast<ushort4*>(P1 + (size_t)row * HID + col) = q;
    q.x = f2bf(s2 * v.x); q.y = f2bf(s2 * v.y); q.z = f2bf(s2 * v.z); q.w = f2bf(s2 * v.w);
    *reinterpret_cast<ushort4*>(P2 + (size_t)row * HID + col) = q;
}

// ---------------------------------------------------------------------------
// 4a) hop-1 gather, A1+A2 fused. Wave w: row i = w>>1, mat = w&1.
__global__ __launch_bounds__(256) void gather_k1(
    const uint16_t* __restrict__ adj1, const uint16_t* __restrict__ adj2,
    const int* __restrict__ deg1p, const int* __restrict__ deg2p,
    const uint32_t* __restrict__ P10, const uint32_t* __restrict__ P20,
    const float* __restrict__ d1, const float* __restrict__ d2,
    uint16_t* __restrict__ rfb, uint16_t* __restrict__ P11, uint16_t* __restrict__ P21)
{
    int gw   = (blockIdx.x * 256 + threadIdx.x) >> 6;
    int lane = threadIdx.x & 63;
    int i    = gw >> 1;
    int mat  = gw & 1;
    int nb = lane >> 4, cq = lane & 15;

    const uint16_t* adj = mat ? adj2 + (size_t)i * CAP2 : adj1 + (size_t)i * CAP1;
    int n = (mat ? deg2p : deg1p)[i];
    const uint32_t* P = mat ? P20 : P10;

    float acc[8] = {};
    #pragma unroll 4
    for (int m = 0; m < n; m += 4) {
        int j = adj[m + nb];
        uint4 u = *reinterpret_cast<const uint4*>(P + (size_t)j * 64 + cq * 4);
        acc[0] += __uint_as_float(u.x << 16);
        acc[1] += __uint_as_float(u.x & 0xffff0000u);
        acc[2] += __uint_as_float(u.y << 16);
        acc[3] += __uint_as_float(u.y & 0xffff0000u);
        acc[4] += __uint_as_float(u.z << 16);
        acc[5] += __uint_as_float(u.z & 0xffff0000u);
        acc[6] += __uint_as_float(u.w << 16);
        acc[7] += __uint_as_float(u.w & 0xffff0000u);
    }
    #pragma unroll
    for (int k = 0; k < 8; ++k) {
        acc[k] += __shfl_xor(acc[k], 16);
        acc[k] += __shfl_xor(acc[k], 32);
    }

    if (nb == 0) {
        float di = (mat ? d2 : d1)[i];
        float o[8];
        #pragma unroll
        for (int k = 0; k < 8; ++k) o[k] = di * acc[k];

        // rf cols 128 + mat*128 + cq*8 .. +8, bf16
        uint4 rv;
        rv.x = packbf(o[0], o[1]); rv.y = packbf(o[2], o[3]);
        rv.z = packbf(o[4], o[5]); rv.w = packbf(o[6], o[7]);
        *reinterpret_cast<uint4*>(rfb + (size_t)i * RF + 128 + mat * 128 + cq * 8) = rv;

        float s1 = d1[i], s2 = d2[i];
        uint32_t* q1 = reinterpret_cast<uint32_t*>(P11) + (size_t)i * 128 + mat * 64 + cq * 4;
        uint32_t* q2 = reinterpret_cast<uint32_t*>(P21) + (size_t)i * 128 + mat * 64 + cq * 4;
        uint4 v1, v2;
        v1.x = packbf(s1 * o[0], s1 * o[1]); v1.y = packbf(s1 * o[2], s1 * o[3]);
        v1.z = packbf(s1 * o[4], s1 * o[5]); v1.w = packbf(s1 * o[6], s1 * o[7]);
        v2.x = packbf(s2 * o[0], s2 * o[1]); v2.y = packbf(s2 * o[2], s2 * o[3]);
        v2.z = packbf(s2 * o[4], s2 * o[5]); v2.w = packbf(s2 * o[6], s2 * o[7]);
        *reinterpret_cast<uint4*>(q1) = v1;
        *reinterpret_cast<uint4*>(q2) = v2;
    }
}

// ---------------------------------------------------------------------------
// 4b) hop-2 gather + fused classifier. One block (4 waves) per row i.
//     Wave: mat=(wv>>1)&1? -> wv = {A1h0, A1h1, A2h0, A2h1} via mat=wv>>1, half=wv&1.
//     After writing its 128 fresh cols, each wave dots them (and a 96-col slice
//     of rf[0:384]) with W_cls; block-reduce -> out[i].
__global__ __launch_bounds__(256) void gather_k2_cls(
    const uint16_t* __restrict__ adj1, const uint16_t* __restrict__ adj2,
    const int* __restrict__ deg1p, const int* __restrict__ deg2p,
    const uint32_t* __restrict__ P11, const uint32_t* __restrict__ P21,
    const float* __restrict__ d1, const float* __restrict__ d2,
    uint16_t* __restrict__ rfb, const float* __restrict__ Wc,
    const float* __restrict__ bc, float* __restrict__ out)
{
    __shared__ float sacc[4][10];

    int wv   = threadIdx.x >> 6;
    int lane = threadIdx.x & 63;
    int i    = blockIdx.x;
    int mat  = wv >> 1;
    int half = wv & 1;
    int nb = lane >> 4, cq = lane & 15;

    const uint16_t* adj = mat ? adj2 + (size_t)i * CAP2 : adj1 + (size_t)i * CAP1;
    int n = (mat ? deg2p : deg1p)[i];
    const uint32_t* P = mat ? P21 : P11;

    float acc[8] = {};
    #pragma unroll 4
    for (int m = 0; m < n; m += 4) {
        int j = adj[m + nb];
        uint4 u = *reinterpret_cast<const uint4*>(P + (size_t)j * 128 + half * 64 + cq * 4);
        acc[0] += __uint_as_float(u.x << 16);
        acc[1] += __uint_as_float(u.x & 0xffff0000u);
        acc[2] += __uint_as_float(u.y << 16);
        acc[3] += __uint_as_float(u.y & 0xffff0000u);
        acc[4] += __uint_as_float(u.z << 16);
        acc[5] += __uint_as_float(u.z & 0xffff0000u);
        acc[6] += __uint_as_float(u.w << 16);
        acc[7] += __uint_as_float(u.w & 0xffff0000u);
    }
    #pragma unroll
    for (int k = 0; k < 8; ++k) {
        acc[k] += __shfl_xor(acc[k], 16);
        acc[k] += __shfl_xor(acc[k], 32);
    }

    float pacc[10] = {};
    if (nb == 0) {
        float di = (mat ? d2 : d1)[i];
        float o[8];
        #pragma unroll
        for (int k = 0; k < 8; ++k) o[k] = di * acc[k];

        int colbase = 384 + mat * 256 + half * 128 + cq * 8;
        uint4 rv;
        rv.x = packbf(o[0], o[1]); rv.y = packbf(o[2], o[3]);
        rv.z = packbf(o[4], o[5]); rv.w = packbf(o[6], o[7]);
        *reinterpret_cast<uint4*>(rfb + (size_t)i * RF + colbase) = rv;

        // fresh-column classifier contribution (exact fp32 o values)
        #pragma unroll
        for (int k = 0; k < 8; ++k) {
            float x = o[k];
            const float* wrow = Wc + (size_t)(colbase + k) * 10;
            #pragma unroll
            for (int c = 0; c < 10; ++c) pacc[c] += x * wrow[c];
        }
    }
    // older cols 0:384, 96 per wave, bf16 pairs
    {
        int cb = (mat * 2 + half) * 96;
        if (lane < 48) {
            uint32_t u = reinterpret_cast<const uint32_t*>(rfb)[(size_t)i * (RF / 2) + cb / 2 + lane];
            float x0 = __uint_as_float(u << 16);
            float x1 = __uint_as_float(u & 0xffff0000u);
            const float* w0 = Wc + (size_t)(cb + lane * 2) * 10;
            #pragma unroll
            for (int c = 0; c < 10; ++c) pacc[c] += x0 * w0[c] + x1 * w0[10 + c];
        }
    }
    #pragma unroll
    for (int c = 0; c < 10; ++c) {
        #pragma unroll
        for (int off = 32; off; off >>= 1) pacc[c] += __shfl_xor(pacc[c], off);
    }
    if (lane == 0) {
        #pragma unroll
        for (int c = 0; c < 10; ++c) sacc[wv][c] = pacc[c];
    }
    __syncthreads();
    if (threadIdx.x < 10) {
        int c = threadIdx.x;
        out[(size_t)i * 10 + c] = sacc[0][c] + sacc[1][c] + sacc[2][c] + sacc[3][c] + bc[c];
    }
}

// ---------------------------------------------------------------------------
extern "C" void kernel_launch(void* const* d_in, const int* in_sizes, int n_in,
                              void* d_out, int out_size, void* d_ws, size_t ws_size,
                              hipStream_t stream) {
    const float* X       = (const float*)d_in[0];
    const int*   ei      = (const int*)d_in[1];
    const float* W_embed = (const float*)d_in[2];
    const float* b_embed = (const float*)d_in[3];
    const float* W_cls   = (const float*)d_in[4];
    const float* b_cls   = (const float*)d_in[5];
    float* out = (float*)d_out;

    int nE = in_sizes[1] / 2;

    // workspace layout (all 16B-aligned)
    uint32_t* Abits = (uint32_t*)d_ws;                         // 2 MB
    float* d1 = (float*)(Abits + (size_t)NN * NW);             // 16 KB
    float* d2 = d1 + NN;                                       // 16 KB
    uint16_t* rfb = (uint16_t*)(d2 + NN);                      // 7.34 MB bf16 [NN][RF]
    uint16_t* P1_0 = rfb + (size_t)NN * RF;                    // [NN+1][128] bf16
    uint16_t* P2_0 = P1_0 + (size_t)(NN + 1) * HID;
    uint16_t* P1_1 = P2_0 + (size_t)(NN + 1) * HID;            // [NN+1][256] bf16
    uint16_t* P2_1 = P1_1 + (size_t)(NN + 1) * 256;
    uint16_t* Wt_hi = P2_1 + (size_t)(NN + 1) * 256;           // 256 KB
    uint16_t* Wt_lo = Wt_hi + (size_t)HID * IN_DIM;            // 256 KB
    float* partials = (float*)(Wt_lo + (size_t)HID * IN_DIM);  // 16 MB [KS][NN][128]
    uint16_t* adj1 = (uint16_t*)(partials + (size_t)KS * NN * HID); // 512 KB
    uint16_t* adj2 = adj1 + (size_t)NN * CAP1;                 // 8 MB
    int* deg1p = (int*)(adj2 + (size_t)NN * CAP2);             // 16 KB
    int* deg2p = deg1p + NN;                                   // 16 KB

    prep<<<641, 256, 0, stream>>>(Abits, (uint32_t*)P1_0, (uint32_t*)P2_0,
                                  (uint32_t*)P1_1, (uint32_t*)P2_1,
                                  W_embed, Wt_hi, Wt_lo);
    scatter_edges<<<(nE + 255) / 256, 256, 0, stream>>>(ei, Abits, nE);
    twohop2<<<NN / 4, 256, 0, stream>>>(Abits, adj1, adj2, deg1p, deg2p, d1, d2);

    embed_mfma<<<dim3(NN / 32, KS), 128, 0, stream>>>(X, Wt_hi, Wt_lo, partials);
    embed_reduce<<<(NN * HID / 4) / 256, 256, 0, stream>>>(partials, b_embed, d1, d2,
                                                           rfb, P1_0, P2_0);

    gather_k1<<<NN * 2 * 64 / 256, 256, 0, stream>>>(
        adj1, adj2, deg1p, deg2p,
        (const uint32_t*)P1_0, (const uint32_t*)P2_0, d1, d2,
        rfb, P1_1, P2_1);
    gather_k2_cls<<<NN, 256, 0, stream>>>(
        adj1, adj2, deg1p, deg2p,
        (const uint32_t*)P1_1, (const uint32_t*)P2_1, d1, d2,
        rfb, W_cls, b_cls, out);
}

// Round 7
// 95.925 us; speedup vs baseline: 2.0927x; 1.0985x over previous
//
#include <hip/hip_runtime.h>
#include <hip/hip_bf16.h>
#include <stdint.h>

// Problem constants (match reference)
#define NN      4096
#define IN_DIM  1024
#define HID     128
#define RF      896          // (2^(K+1)-1)*HID
#define NW      128          // words per bitmask row (4096/32)
#define CAP1    64           // adj1 stride (1-hop deg ~16, max ~40)
#define CAP2    1024         // adj2 stride (2-hop deg ~240)
#define KS      8            // split-K chunks for embed gemm
#define KC      (IN_DIM/KS)  // 128

typedef __attribute__((ext_vector_type(8))) short   bf16x8;
typedef __attribute__((ext_vector_type(4))) float   f32x4;
typedef __attribute__((ext_vector_type(2))) float   f32x2;

static __device__ __forceinline__ uint16_t f2bf(float f) {
    __hip_bfloat16 h = __float2bfloat16(f);   // RNE
    return *reinterpret_cast<uint16_t*>(&h);
}
static __device__ __forceinline__ float bf2f(uint16_t u) {
    __hip_bfloat16 h = *reinterpret_cast<__hip_bfloat16*>(&u);
    return __bfloat162float(h);
}
static __device__ __forceinline__ uint32_t packbf(float lo, float hi) {
    return (uint32_t)f2bf(lo) | ((uint32_t)f2bf(hi) << 16);
}

// ---------------------------------------------------------------------------
// 0) prep: zero Abits (blocks 0..511), zero P pad rows (block 512),
//    convert W -> transposed bf16 hi/lo (blocks 513..640, 128 thr active)
__global__ __launch_bounds__(256) void prep(
    uint32_t* __restrict__ Abits, uint32_t* __restrict__ p10, uint32_t* __restrict__ p20,
    uint32_t* __restrict__ p11, uint32_t* __restrict__ p21,
    const float* __restrict__ W, uint16_t* __restrict__ Wt_hi, uint16_t* __restrict__ Wt_lo)
{
    int b = blockIdx.x, t = threadIdx.x;
    if (b < 512) {
        reinterpret_cast<uint4*>(Abits)[b * 256 + t] = make_uint4(0, 0, 0, 0);
    } else if (b == 512) {
        if (t < 64)  { p10[(size_t)NN * 64 + t] = 0;  p20[(size_t)NN * 64 + t] = 0; }
        if (t < 128) { p11[(size_t)NN * 128 + t] = 0; p21[(size_t)NN * 128 + t] = 0; }
    } else {
        if (t < 128) {
            int n  = t;
            int k0 = (b - 513) * 8;
            uint16_t h[8], l[8];
            #pragma unroll
            for (int j = 0; j < 8; ++j) {
                float x = W[(size_t)(k0 + j) * HID + n];
                h[j] = f2bf(x);
                l[j] = f2bf(x - bf2f(h[j]));
            }
            ushort4* ph = reinterpret_cast<ushort4*>(Wt_hi + (size_t)n * IN_DIM + k0);
            ushort4* pl = reinterpret_cast<ushort4*>(Wt_lo + (size_t)n * IN_DIM + k0);
            ph[0] = make_ushort4(h[0], h[1], h[2], h[3]);
            ph[1] = make_ushort4(h[4], h[5], h[6], h[7]);
            pl[0] = make_ushort4(l[0], l[1], l[2], l[3]);
            pl[1] = make_ushort4(l[4], l[5], l[6], l[7]);
        }
    }
}

// ---------------------------------------------------------------------------
// 1) scatter edges into bitmask adjacency  A[src][dst] = 1
__global__ void scatter_edges(const int* __restrict__ ei, uint32_t* __restrict__ Abits, int nE) {
    int e = blockIdx.x * blockDim.x + threadIdx.x;
    if (e < nE) {
        int s = ei[e];
        int d = ei[nE + e];
        atomicOr(&Abits[(size_t)s * NW + (d >> 5)], 1u << (d & 31));
    }
}

// ---------------------------------------------------------------------------
// 2) twohop2: bit-sliced threshold counters, wave-per-row (4 waves/block).
#define UPD(v) { s3x |= s2x & (v).x; s2x |= s1x & (v).x; s1x |= (v).x; \
                 s3y |= s2y & (v).y; s2y |= s1y & (v).y; s1y |= (v).y; }
__global__ __launch_bounds__(256) void twohop2(
    const uint32_t* __restrict__ Abits,
    uint16_t* __restrict__ adj1, uint16_t* __restrict__ adj2,
    int* __restrict__ deg1p, int* __restrict__ deg2p,
    float* __restrict__ d1, float* __restrict__ d2)
{
    __shared__ uint16_t l1s[4][CAP1];

    int wv = threadIdx.x >> 6, lane = threadIdx.x & 63;
    int i = blockIdx.x * 4 + wv;

    uint2 sv = *reinterpret_cast<const uint2*>(&Abits[(size_t)i * NW + lane * 2]);

    // ---- adj1: scan + emit
    int pc1 = __popc(sv.x) + __popc(sv.y);
    int x1 = pc1;
    #pragma unroll
    for (int off = 1; off < 64; off <<= 1) {
        int y = __shfl_up(x1, off);
        if (lane >= off) x1 += y;
    }
    int tot1 = __shfl(x1, 63);
    int o = x1 - pc1;                       // exclusive prefix
    {
        uint32_t b = sv.x;
        while (b) { int bb = __ffs(b) - 1; b &= b - 1;
                    uint16_t v = (uint16_t)(lane * 64 + bb);
                    l1s[wv][o] = v; adj1[(size_t)i * CAP1 + o] = v; ++o; }
        b = sv.y;
        while (b) { int bb = __ffs(b) - 1; b &= b - 1;
                    uint16_t v = (uint16_t)(lane * 64 + 32 + bb);
                    l1s[wv][o] = v; adj1[(size_t)i * CAP1 + o] = v; ++o; }
    }
    int n1 = (tot1 + 3) & ~3;
    if (lane == 0) {
        for (int z = tot1; z < n1; ++z) adj1[(size_t)i * CAP1 + z] = (uint16_t)NN;
        deg1p[i] = n1;
        d1[i] = rsqrtf((float)tot1 + 1e-8f);
    }
    __syncthreads();

    // ---- path-count thresholds over neighbors
    uint32_t s1x = 0, s2x = 0, s3x = 0, s1y = 0, s2y = 0, s3y = 0;
    int m = 0;
    for (; m + 4 <= tot1; m += 4) {
        int k0 = l1s[wv][m], k1 = l1s[wv][m + 1], k2 = l1s[wv][m + 2], k3 = l1s[wv][m + 3];
        uint2 a = *reinterpret_cast<const uint2*>(&Abits[(size_t)k0 * NW + lane * 2]);
        uint2 b = *reinterpret_cast<const uint2*>(&Abits[(size_t)k1 * NW + lane * 2]);
        uint2 c = *reinterpret_cast<const uint2*>(&Abits[(size_t)k2 * NW + lane * 2]);
        uint2 d = *reinterpret_cast<const uint2*>(&Abits[(size_t)k3 * NW + lane * 2]);
        UPD(a); UPD(b); UPD(c); UPD(d);
    }
    for (; m < tot1; ++m) {
        int k = l1s[wv][m];
        uint2 a = *reinterpret_cast<const uint2*>(&Abits[(size_t)k * NW + lane * 2]);
        UPD(a);
    }

    uint32_t iwx = ((i >> 5) == lane * 2)     ? (1u << (i & 31)) : 0u;
    uint32_t iwy = ((i >> 5) == lane * 2 + 1) ? (1u << (i & 31)) : 0u;
    uint32_t a2x = (s1x & ~sv.x & ~iwx) | (s2x & (sv.x ^ iwx)) | (s3x & (sv.x & iwx));
    uint32_t a2y = (s1y & ~sv.y & ~iwy) | (s2y & (sv.y ^ iwy)) | (s3y & (sv.y & iwy));

    // ---- adj2: scan + emit
    int pc2 = __popc(a2x) + __popc(a2y);
    int x2 = pc2;
    #pragma unroll
    for (int off = 1; off < 64; off <<= 1) {
        int y = __shfl_up(x2, off);
        if (lane >= off) x2 += y;
    }
    int tot2 = __shfl(x2, 63);
    o = x2 - pc2;
    {
        uint32_t b = a2x;
        while (b) { int bb = __ffs(b) - 1; b &= b - 1;
                    adj2[(size_t)i * CAP2 + o] = (uint16_t)(lane * 64 + bb); ++o; }
        b = a2y;
        while (b) { int bb = __ffs(b) - 1; b &= b - 1;
                    adj2[(size_t)i * CAP2 + o] = (uint16_t)(lane * 64 + 32 + bb); ++o; }
    }
    int n2 = (tot2 + 3) & ~3;
    if (lane == 0) {
        for (int z = tot2; z < n2; ++z) adj2[(size_t)i * CAP2 + z] = (uint16_t)NN;
        deg2p[i] = n2;
        d2[i] = rsqrtf((float)tot2 + 1e-8f);
    }
}

// ---------------------------------------------------------------------------
// 3b) embed MFMA GEMM, bf16x2 split, split-K
#define XSTR 136
__global__ __launch_bounds__(128) void embed_mfma(
    const float* __restrict__ X, const uint16_t* __restrict__ Wt_hi,
    const uint16_t* __restrict__ Wt_lo, float* __restrict__ partials)
{
    __shared__ uint16_t XhiS[32][XSTR];
    __shared__ uint16_t XloS[32][XSTR];
    __shared__ uint16_t WS[128][XSTR];

    int t  = threadIdx.x;
    int m0 = blockIdx.x * 32;
    int kc = blockIdx.y;

    #pragma unroll
    for (int u = 0; u < 8; ++u) {
        int q = u * 128 + t;
        int row = q >> 5, c4 = q & 31;
        float4 xv = *reinterpret_cast<const float4*>(
            X + (size_t)(m0 + row) * IN_DIM + kc * KC + c4 * 4);
        ushort4 hv, lv;
        hv.x = f2bf(xv.x); lv.x = f2bf(xv.x - bf2f(hv.x));
        hv.y = f2bf(xv.y); lv.y = f2bf(xv.y - bf2f(hv.y));
        hv.z = f2bf(xv.z); lv.z = f2bf(xv.z - bf2f(hv.z));
        hv.w = f2bf(xv.w); lv.w = f2bf(xv.w - bf2f(hv.w));
        *reinterpret_cast<ushort4*>(&XhiS[row][c4 * 4]) = hv;
        *reinterpret_cast<ushort4*>(&XloS[row][c4 * 4]) = lv;
    }
    #pragma unroll
    for (int u = 0; u < 16; ++u) {
        int q = u * 128 + t;
        int n = q >> 4, ck = q & 15;
        *reinterpret_cast<uint4*>(&WS[n][ck * 8]) =
            *reinterpret_cast<const uint4*>(Wt_hi + (size_t)n * IN_DIM + kc * KC + ck * 8);
    }
    __syncthreads();

    int w = t >> 6, lane = t & 63;
    int nr = lane & 15, g = lane >> 4;
    int arow = w * 16 + nr;

    bf16x8 ah[4], al[4];
    #pragma unroll
    for (int s = 0; s < 4; ++s) {
        ah[s] = *reinterpret_cast<const bf16x8*>(&XhiS[arow][s * 32 + g * 8]);
        al[s] = *reinterpret_cast<const bf16x8*>(&XloS[arow][s * 32 + g * 8]);
    }

    f32x4 acc[8] = {};

    #pragma unroll
    for (int s = 0; s < 4; ++s)
        #pragma unroll
        for (int nf = 0; nf < 8; ++nf) {
            bf16x8 bb = *reinterpret_cast<const bf16x8*>(&WS[nf * 16 + nr][s * 32 + g * 8]);
            acc[nf] = __builtin_amdgcn_mfma_f32_16x16x32_bf16(ah[s], bb, acc[nf], 0, 0, 0);
            acc[nf] = __builtin_amdgcn_mfma_f32_16x16x32_bf16(al[s], bb, acc[nf], 0, 0, 0);
        }
    __syncthreads();
    #pragma unroll
    for (int u = 0; u < 16; ++u) {
        int q = u * 128 + t;
        int n = q >> 4, ck = q & 15;
        *reinterpret_cast<uint4*>(&WS[n][ck * 8]) =
            *reinterpret_cast<const uint4*>(Wt_lo + (size_t)n * IN_DIM + kc * KC + ck * 8);
    }
    __syncthreads();
    #pragma unroll
    for (int s = 0; s < 4; ++s)
        #pragma unroll
        for (int nf = 0; nf < 8; ++nf) {
            bf16x8 bb = *reinterpret_cast<const bf16x8*>(&WS[nf * 16 + nr][s * 32 + g * 8]);
            acc[nf] = __builtin_amdgcn_mfma_f32_16x16x32_bf16(ah[s], bb, acc[nf], 0, 0, 0);
        }

    float* part = partials + (size_t)kc * NN * HID;
    #pragma unroll
    for (int nf = 0; nf < 8; ++nf)
        #pragma unroll
        for (int r = 0; r < 4; ++r)
            part[(size_t)(m0 + w * 16 + g * 4 + r) * HID + nf * 16 + nr] = acc[nf][r];
}

// ---------------------------------------------------------------------------
// 3c) reduce split-K partials + bias + relu -> rf bf16 (cols 0:128) + P1_0/P2_0
__global__ void embed_reduce(const float* __restrict__ partials, const float* __restrict__ bias,
                             const float* __restrict__ d1, const float* __restrict__ d2,
                             uint16_t* __restrict__ rfb, uint16_t* __restrict__ P1,
                             uint16_t* __restrict__ P2) {
    int idx = blockIdx.x * blockDim.x + threadIdx.x;
    size_t off = (size_t)idx * 4;
    int row = (int)(off >> 7);
    int col = (int)(off & 127);

    float4 s = make_float4(0.f, 0.f, 0.f, 0.f);
    #pragma unroll
    for (int kc = 0; kc < KS; ++kc) {
        float4 p = *reinterpret_cast<const float4*>(partials + (size_t)kc * NN * HID + off);
        s.x += p.x; s.y += p.y; s.z += p.z; s.w += p.w;
    }
    float4 bv = *reinterpret_cast<const float4*>(bias + col);
    float4 v;
    v.x = fmaxf(s.x + bv.x, 0.f);
    v.y = fmaxf(s.y + bv.y, 0.f);
    v.z = fmaxf(s.z + bv.z, 0.f);
    v.w = fmaxf(s.w + bv.w, 0.f);

    uint2 rv;
    rv.x = packbf(v.x, v.y); rv.y = packbf(v.z, v.w);
    *reinterpret_cast<uint2*>(rfb + (size_t)row * RF + col) = rv;

    float s1 = d1[row], s2 = d2[row];
    ushort4 q;
    q.x = f2bf(s1 * v.x); q.y = f2bf(s1 * v.y); q.z = f2bf(s1 * v.z); q.w = f2bf(s1 * v.w);
    *reinterpret_cast<ushort4*>(P1 + (size_t)row * HID + col) = q;
    q.x = f2bf(s2 * v.x); q.y = f2bf(s2 * v.y); q.z = f2bf(s2 * v.z); q.w = f2bf(s2 * v.w);
    *reinterpret_cast<ushort4*>(P2 + (size_t)row * HID + col) = q;
}

// ---------------------------------------------------------------------------
// 4a) hop-1 gather, A1+A2 fused. Wave w: row i = w>>1, mat = w&1. No barriers.
__global__ __launch_bounds__(256) void gather_k1(
    const uint16_t* __restrict__ adj1, const uint16_t* __restrict__ adj2,
    const int* __restrict__ deg1p, const int* __restrict__ deg2p,
    const uint32_t* __restrict__ P10, const uint32_t* __restrict__ P20,
    const float* __restrict__ d1, const float* __restrict__ d2,
    uint16_t* __restrict__ rfb, uint16_t* __restrict__ P11, uint16_t* __restrict__ P21)
{
    int gw   = (blockIdx.x * 256 + threadIdx.x) >> 6;
    int lane = threadIdx.x & 63;
    int i    = gw >> 1;
    int mat  = gw & 1;
    int nb = lane >> 4, cq = lane & 15;

    const uint16_t* adj = mat ? adj2 + (size_t)i * CAP2 : adj1 + (size_t)i * CAP1;
    int n = (mat ? deg2p : deg1p)[i];
    const uint32_t* P = mat ? P20 : P10;

    f32x2 acc[4] = {};
    #pragma unroll 8
    for (int m = 0; m < n; m += 4) {
        int j = adj[m + nb];
        uint4 u = *reinterpret_cast<const uint4*>(P + (size_t)j * 64 + cq * 4);
        acc[0] += (f32x2){__uint_as_float(u.x << 16), __uint_as_float(u.x & 0xffff0000u)};
        acc[1] += (f32x2){__uint_as_float(u.y << 16), __uint_as_float(u.y & 0xffff0000u)};
        acc[2] += (f32x2){__uint_as_float(u.z << 16), __uint_as_float(u.z & 0xffff0000u)};
        acc[3] += (f32x2){__uint_as_float(u.w << 16), __uint_as_float(u.w & 0xffff0000u)};
    }
    #pragma unroll
    for (int k = 0; k < 4; ++k) {
        acc[k].x += __shfl_xor(acc[k].x, 16); acc[k].y += __shfl_xor(acc[k].y, 16);
        acc[k].x += __shfl_xor(acc[k].x, 32); acc[k].y += __shfl_xor(acc[k].y, 32);
    }

    if (nb == 0) {
        float di = (mat ? d2 : d1)[i];
        float o[8];
        #pragma unroll
        for (int k = 0; k < 4; ++k) { o[2 * k] = di * acc[k].x; o[2 * k + 1] = di * acc[k].y; }

        uint4 rv;
        rv.x = packbf(o[0], o[1]); rv.y = packbf(o[2], o[3]);
        rv.z = packbf(o[4], o[5]); rv.w = packbf(o[6], o[7]);
        *reinterpret_cast<uint4*>(rfb + (size_t)i * RF + 128 + mat * 128 + cq * 8) = rv;

        float s1 = d1[i], s2 = d2[i];
        uint32_t* q1 = reinterpret_cast<uint32_t*>(P11) + (size_t)i * 128 + mat * 64 + cq * 4;
        uint32_t* q2 = reinterpret_cast<uint32_t*>(P21) + (size_t)i * 128 + mat * 64 + cq * 4;
        uint4 v1, v2;
        v1.x = packbf(s1 * o[0], s1 * o[1]); v1.y = packbf(s1 * o[2], s1 * o[3]);
        v1.z = packbf(s1 * o[4], s1 * o[5]); v1.w = packbf(s1 * o[6], s1 * o[7]);
        v2.x = packbf(s2 * o[0], s2 * o[1]); v2.y = packbf(s2 * o[2], s2 * o[3]);
        v2.z = packbf(s2 * o[4], s2 * o[5]); v2.w = packbf(s2 * o[6], s2 * o[7]);
        *reinterpret_cast<uint4*>(q1) = v1;
        *reinterpret_cast<uint4*>(q2) = v2;
    }
}

// ---------------------------------------------------------------------------
// 4b) hop-2 gather, standalone, barrier-free, segment-grouped for balance.
//     Grid 4096 blocks: seg = b>>10 (mat=seg>>1, half=seg&1), row = (b&1023)*4+wv.
__global__ __launch_bounds__(256) void gather_k2(
    const uint16_t* __restrict__ adj1, const uint16_t* __restrict__ adj2,
    const int* __restrict__ deg1p, const int* __restrict__ deg2p,
    const uint32_t* __restrict__ P11, const uint32_t* __restrict__ P21,
    const float* __restrict__ d1, const float* __restrict__ d2,
    uint16_t* __restrict__ rfb)
{
    int wv   = threadIdx.x >> 6;
    int lane = threadIdx.x & 63;
    int seg  = blockIdx.x >> 10;
    int i    = (blockIdx.x & 1023) * 4 + wv;
    int mat  = seg >> 1;
    int half = seg & 1;
    int nb = lane >> 4, cq = lane & 15;

    const uint16_t* adj = mat ? adj2 + (size_t)i * CAP2 : adj1 + (size_t)i * CAP1;
    int n = (mat ? deg2p : deg1p)[i];
    const uint32_t* P = mat ? P21 : P11;

    f32x2 acc[4] = {};
    #pragma unroll 8
    for (int m = 0; m < n; m += 4) {
        int j = adj[m + nb];
        uint4 u = *reinterpret_cast<const uint4*>(P + (size_t)j * 128 + half * 64 + cq * 4);
        acc[0] += (f32x2){__uint_as_float(u.x << 16), __uint_as_float(u.x & 0xffff0000u)};
        acc[1] += (f32x2){__uint_as_float(u.y << 16), __uint_as_float(u.y & 0xffff0000u)};
        acc[2] += (f32x2){__uint_as_float(u.z << 16), __uint_as_float(u.z & 0xffff0000u)};
        acc[3] += (f32x2){__uint_as_float(u.w << 16), __uint_as_float(u.w & 0xffff0000u)};
    }
    #pragma unroll
    for (int k = 0; k < 4; ++k) {
        acc[k].x += __shfl_xor(acc[k].x, 16); acc[k].y += __shfl_xor(acc[k].y, 16);
        acc[k].x += __shfl_xor(acc[k].x, 32); acc[k].y += __shfl_xor(acc[k].y, 32);
    }

    if (nb == 0) {
        float di = (mat ? d2 : d1)[i];
        int colbase = 384 + mat * 256 + half * 128 + cq * 8;
        uint4 rv;
        rv.x = packbf(di * acc[0].x, di * acc[0].y);
        rv.y = packbf(di * acc[1].x, di * acc[1].y);
        rv.z = packbf(di * acc[2].x, di * acc[2].y);
        rv.w = packbf(di * acc[3].x, di * acc[3].y);
        *reinterpret_cast<uint4*>(rfb + (size_t)i * RF + colbase) = rv;
    }
}

// ---------------------------------------------------------------------------
// 5) classifier GEMM over bf16 rf: out = rf @ Wc + bc. Wave-per-row.
__global__ __launch_bounds__(256) void cls_bf(
    const uint16_t* __restrict__ rfb, const float* __restrict__ Wc,
    const float* __restrict__ bc, float* __restrict__ out)
{
    int wave = threadIdx.x >> 6;
    int lane = threadIdx.x & 63;
    int row  = blockIdx.x * 4 + wave;

    const uint32_t* rp = reinterpret_cast<const uint32_t*>(rfb + (size_t)row * RF);
    float acc[10] = {};
    #pragma unroll
    for (int k7 = 0; k7 < 7; ++k7) {
        int k = k7 * 64 + lane;          // uint index 0..447 (col pair 2k,2k+1)
        uint32_t u = rp[k];
        float x0 = __uint_as_float(u << 16);
        float x1 = __uint_as_float(u & 0xffff0000u);
        const float* w = Wc + (size_t)k * 20;
        #pragma unroll
        for (int c = 0; c < 10; ++c) acc[c] += x0 * w[c] + x1 * w[10 + c];
    }
    #pragma unroll
    for (int c = 0; c < 10; ++c)
        #pragma unroll
        for (int off = 32; off; off >>= 1) acc[c] += __shfl_down(acc[c], off);

    if (lane == 0) {
        #pragma unroll
        for (int c = 0; c < 10; ++c) out[(size_t)row * 10 + c] = acc[c] + bc[c];
    }
}

// ---------------------------------------------------------------------------
extern "C" void kernel_launch(void* const* d_in, const int* in_sizes, int n_in,
                              void* d_out, int out_size, void* d_ws, size_t ws_size,
                              hipStream_t stream) {
    const float* X       = (const float*)d_in[0];
    const int*   ei      = (const int*)d_in[1];
    const float* W_embed = (const float*)d_in[2];
    const float* b_embed = (const float*)d_in[3];
    const float* W_cls   = (const float*)d_in[4];
    const float* b_cls   = (const float*)d_in[5];
    float* out = (float*)d_out;

    int nE = in_sizes[1] / 2;

    // workspace layout (all 16B-aligned)
    uint32_t* Abits = (uint32_t*)d_ws;                         // 2 MB
    float* d1 = (float*)(Abits + (size_t)NN * NW);             // 16 KB
    float* d2 = d1 + NN;                                       // 16 KB
    uint16_t* rfb = (uint16_t*)(d2 + NN);                      // 7.34 MB bf16 [NN][RF]
    uint16_t* P1_0 = rfb + (size_t)NN * RF;                    // [NN+1][128] bf16
    uint16_t* P2_0 = P1_0 + (size_t)(NN + 1) * HID;
    uint16_t* P1_1 = P2_0 + (size_t)(NN + 1) * HID;            // [NN+1][256] bf16
    uint16_t* P2_1 = P1_1 + (size_t)(NN + 1) * 256;
    uint16_t* Wt_hi = P2_1 + (size_t)(NN + 1) * 256;           // 256 KB
    uint16_t* Wt_lo = Wt_hi + (size_t)HID * IN_DIM;            // 256 KB
    float* partials = (float*)(Wt_lo + (size_t)HID * IN_DIM);  // 16 MB [KS][NN][128]
    uint16_t* adj1 = (uint16_t*)(partials + (size_t)KS * NN * HID); // 512 KB
    uint16_t* adj2 = adj1 + (size_t)NN * CAP1;                 // 8 MB
    int* deg1p = (int*)(adj2 + (size_t)NN * CAP2);             // 16 KB
    int* deg2p = deg1p + NN;                                   // 16 KB

    prep<<<641, 256, 0, stream>>>(Abits, (uint32_t*)P1_0, (uint32_t*)P2_0,
                                  (uint32_t*)P1_1, (uint32_t*)P2_1,
                                  W_embed, Wt_hi, Wt_lo);
    scatter_edges<<<(nE + 255) / 256, 256, 0, stream>>>(ei, Abits, nE);
    twohop2<<<NN / 4, 256, 0, stream>>>(Abits, adj1, adj2, deg1p, deg2p, d1, d2);

    embed_mfma<<<dim3(NN / 32, KS), 128, 0, stream>>>(X, Wt_hi, Wt_lo, partials);
    embed_reduce<<<(NN * HID / 4) / 256, 256, 0, stream>>>(partials, b_embed, d1, d2,
                                                           rfb, P1_0, P2_0);

    gather_k1<<<NN * 2 * 64 / 256, 256, 0, stream>>>(
        adj1, adj2, deg1p, deg2p,
        (const uint32_t*)P1_0, (const uint32_t*)P2_0, d1, d2,
        rfb, P1_1, P2_1);
    gather_k2<<<NN * 4 * 64 / 256, 256, 0, stream>>>(
        adj1, adj2, deg1p, deg2p,
        (const uint32_t*)P1_1, (const uint32_t*)P2_1, d1, d2, rfb);

    cls_bf<<<NN / 4, 256, 0, stream>>>(rfb, W_cls, b_cls, out);
}

// Round 9
// 92.109 us; speedup vs baseline: 2.1794x; 1.0414x over previous
//
#include <hip/hip_runtime.h>
#include <hip/hip_bf16.h>
#include <stdint.h>

// Problem constants (match reference)
#define NN      4096
#define IN_DIM  1024
#define HID     128
#define RF      896          // (2^(K+1)-1)*HID
#define NW      128          // words per bitmask row (4096/32)
#define CAP1    64           // adj1 stride (1-hop deg ~16, max ~40)
#define CAP2    1024         // adj2 stride (2-hop deg ~240)
#define KS      8            // split-K chunks for embed gemm
#define KC      (IN_DIM/KS)  // 128

typedef __attribute__((ext_vector_type(8))) short   bf16x8;
typedef __attribute__((ext_vector_type(4))) float   f32x4;
typedef __attribute__((ext_vector_type(2))) float   f32x2;

static __device__ __forceinline__ uint16_t f2bf(float f) {
    __hip_bfloat16 h = __float2bfloat16(f);   // RNE
    return *reinterpret_cast<uint16_t*>(&h);
}
static __device__ __forceinline__ float bf2f(uint16_t u) {
    __hip_bfloat16 h = *reinterpret_cast<__hip_bfloat16*>(&u);
    return __bfloat162float(h);
}
static __device__ __forceinline__ uint32_t packbf(float lo, float hi) {
    return (uint32_t)f2bf(lo) | ((uint32_t)f2bf(hi) << 16);
}

// ---------------------------------------------------------------------------
// 0) prep: zero Abits (blocks 0..511), zero P pad rows (block 512),
//    convert W -> transposed bf16 hi/lo (blocks 513..640, 128 thr active)
__global__ __launch_bounds__(256) void prep(
    uint32_t* __restrict__ Abits, uint32_t* __restrict__ p10, uint32_t* __restrict__ p20,
    uint32_t* __restrict__ p11, uint32_t* __restrict__ p21,
    const float* __restrict__ W, uint16_t* __restrict__ Wt_hi, uint16_t* __restrict__ Wt_lo)
{
    int b = blockIdx.x, t = threadIdx.x;
    if (b < 512) {
        reinterpret_cast<uint4*>(Abits)[b * 256 + t] = make_uint4(0, 0, 0, 0);
    } else if (b == 512) {
        if (t < 64)  { p10[(size_t)NN * 64 + t] = 0;  p20[(size_t)NN * 64 + t] = 0; }
        if (t < 128) { p11[(size_t)NN * 128 + t] = 0; p21[(size_t)NN * 128 + t] = 0; }
    } else {
        if (t < 128) {
            int n  = t;
            int k0 = (b - 513) * 8;
            uint16_t h[8], l[8];
            #pragma unroll
            for (int j = 0; j < 8; ++j) {
                float x = W[(size_t)(k0 + j) * HID + n];
                h[j] = f2bf(x);
                l[j] = f2bf(x - bf2f(h[j]));
            }
            ushort4* ph = reinterpret_cast<ushort4*>(Wt_hi + (size_t)n * IN_DIM + k0);
            ushort4* pl = reinterpret_cast<ushort4*>(Wt_lo + (size_t)n * IN_DIM + k0);
            ph[0] = make_ushort4(h[0], h[1], h[2], h[3]);
            ph[1] = make_ushort4(h[4], h[5], h[6], h[7]);
            pl[0] = make_ushort4(l[0], l[1], l[2], l[3]);
            pl[1] = make_ushort4(l[4], l[5], l[6], l[7]);
        }
    }
}

// ---------------------------------------------------------------------------
// 1) scatter edges into bitmask adjacency  A[src][dst] = 1
__global__ void scatter_edges(const int* __restrict__ ei, uint32_t* __restrict__ Abits, int nE) {
    int e = blockIdx.x * blockDim.x + threadIdx.x;
    if (e < nE) {
        int s = ei[e];
        int d = ei[nE + e];
        atomicOr(&Abits[(size_t)s * NW + (d >> 5)], 1u << (d & 31));
    }
}

// ---------------------------------------------------------------------------
// 2) twohop2: bit-sliced threshold counters, wave-per-row (4 waves/block).
#define UPD(v) { s3x |= s2x & (v).x; s2x |= s1x & (v).x; s1x |= (v).x; \
                 s3y |= s2y & (v).y; s2y |= s1y & (v).y; s1y |= (v).y; }
__global__ __launch_bounds__(256) void twohop2(
    const uint32_t* __restrict__ Abits,
    uint16_t* __restrict__ adj1, uint16_t* __restrict__ adj2,
    int* __restrict__ deg1p, int* __restrict__ deg2p,
    float* __restrict__ d1, float* __restrict__ d2)
{
    __shared__ uint16_t l1s[4][CAP1];

    int wv = threadIdx.x >> 6, lane = threadIdx.x & 63;
    int i = blockIdx.x * 4 + wv;

    uint2 sv = *reinterpret_cast<const uint2*>(&Abits[(size_t)i * NW + lane * 2]);

    // ---- adj1: scan + emit
    int pc1 = __popc(sv.x) + __popc(sv.y);
    int x1 = pc1;
    #pragma unroll
    for (int off = 1; off < 64; off <<= 1) {
        int y = __shfl_up(x1, off);
        if (lane >= off) x1 += y;
    }
    int tot1 = __shfl(x1, 63);
    int o = x1 - pc1;                       // exclusive prefix
    {
        uint32_t b = sv.x;
        while (b) { int bb = __ffs(b) - 1; b &= b - 1;
                    uint16_t v = (uint16_t)(lane * 64 + bb);
                    l1s[wv][o] = v; adj1[(size_t)i * CAP1 + o] = v; ++o; }
        b = sv.y;
        while (b) { int bb = __ffs(b) - 1; b &= b - 1;
                    uint16_t v = (uint16_t)(lane * 64 + 32 + bb);
                    l1s[wv][o] = v; adj1[(size_t)i * CAP1 + o] = v; ++o; }
    }
    int n1 = (tot1 + 3) & ~3;
    if (lane == 0) {
        for (int z = tot1; z < n1; ++z) adj1[(size_t)i * CAP1 + z] = (uint16_t)NN;
        deg1p[i] = n1;
        d1[i] = rsqrtf((float)tot1 + 1e-8f);
    }
    __syncthreads();

    // ---- path-count thresholds over neighbors
    uint32_t s1x = 0, s2x = 0, s3x = 0, s1y = 0, s2y = 0, s3y = 0;
    int m = 0;
    for (; m + 4 <= tot1; m += 4) {
        int k0 = l1s[wv][m], k1 = l1s[wv][m + 1], k2 = l1s[wv][m + 2], k3 = l1s[wv][m + 3];
        uint2 a = *reinterpret_cast<const uint2*>(&Abits[(size_t)k0 * NW + lane * 2]);
        uint2 b = *reinterpret_cast<const uint2*>(&Abits[(size_t)k1 * NW + lane * 2]);
        uint2 c = *reinterpret_cast<const uint2*>(&Abits[(size_t)k2 * NW + lane * 2]);
        uint2 d = *reinterpret_cast<const uint2*>(&Abits[(size_t)k3 * NW + lane * 2]);
        UPD(a); UPD(b); UPD(c); UPD(d);
    }
    for (; m < tot1; ++m) {
        int k = l1s[wv][m];
        uint2 a = *reinterpret_cast<const uint2*>(&Abits[(size_t)k * NW + lane * 2]);
        UPD(a);
    }

    uint32_t iwx = ((i >> 5) == lane * 2)     ? (1u << (i & 31)) : 0u;
    uint32_t iwy = ((i >> 5) == lane * 2 + 1) ? (1u << (i & 31)) : 0u;
    uint32_t a2x = (s1x & ~sv.x & ~iwx) | (s2x & (sv.x ^ iwx)) | (s3x & (sv.x & iwx));
    uint32_t a2y = (s1y & ~sv.y & ~iwy) | (s2y & (sv.y ^ iwy)) | (s3y & (sv.y & iwy));

    // ---- adj2: scan + emit
    int pc2 = __popc(a2x) + __popc(a2y);
    int x2 = pc2;
    #pragma unroll
    for (int off = 1; off < 64; off <<= 1) {
        int y = __shfl_up(x2, off);
        if (lane >= off) x2 += y;
    }
    int tot2 = __shfl(x2, 63);
    o = x2 - pc2;
    {
        uint32_t b = a2x;
        while (b) { int bb = __ffs(b) - 1; b &= b - 1;
                    adj2[(size_t)i * CAP2 + o] = (uint16_t)(lane * 64 + bb); ++o; }
        b = a2y;
        while (b) { int bb = __ffs(b) - 1; b &= b - 1;
                    adj2[(size_t)i * CAP2 + o] = (uint16_t)(lane * 64 + 32 + bb); ++o; }
    }
    int n2 = (tot2 + 3) & ~3;
    if (lane == 0) {
        for (int z = tot2; z < n2; ++z) adj2[(size_t)i * CAP2 + z] = (uint16_t)NN;
        deg2p[i] = n2;
        d2[i] = rsqrtf((float)tot2 + 1e-8f);
    }
}

// ---------------------------------------------------------------------------
// 3b) embed MFMA GEMM, bf16x2 split, split-K
#define XSTR 136
__global__ __launch_bounds__(128) void embed_mfma(
    const float* __restrict__ X, const uint16_t* __restrict__ Wt_hi,
    const uint16_t* __restrict__ Wt_lo, float* __restrict__ partials)
{
    __shared__ uint16_t XhiS[32][XSTR];
    __shared__ uint16_t XloS[32][XSTR];
    __shared__ uint16_t WS[128][XSTR];

    int t  = threadIdx.x;
    int m0 = blockIdx.x * 32;
    int kc = blockIdx.y;

    #pragma unroll
    for (int u = 0; u < 8; ++u) {
        int q = u * 128 + t;
        int row = q >> 5, c4 = q & 31;
        float4 xv = *reinterpret_cast<const float4*>(
            X + (size_t)(m0 + row) * IN_DIM + kc * KC + c4 * 4);
        ushort4 hv, lv;
        hv.x = f2bf(xv.x); lv.x = f2bf(xv.x - bf2f(hv.x));
        hv.y = f2bf(xv.y); lv.y = f2bf(xv.y - bf2f(hv.y));
        hv.z = f2bf(xv.z); lv.z = f2bf(xv.z - bf2f(hv.z));
        hv.w = f2bf(xv.w); lv.w = f2bf(xv.w - bf2f(hv.w));
        *reinterpret_cast<ushort4*>(&XhiS[row][c4 * 4]) = hv;
        *reinterpret_cast<ushort4*>(&XloS[row][c4 * 4]) = lv;
    }
    #pragma unroll
    for (int u = 0; u < 16; ++u) {
        int q = u * 128 + t;
        int n = q >> 4, ck = q & 15;
        *reinterpret_cast<uint4*>(&WS[n][ck * 8]) =
            *reinterpret_cast<const uint4*>(Wt_hi + (size_t)n * IN_DIM + kc * KC + ck * 8);
    }
    __syncthreads();

    int w = t >> 6, lane = t & 63;
    int nr = lane & 15, g = lane >> 4;
    int arow = w * 16 + nr;

    bf16x8 ah[4], al[4];
    #pragma unroll
    for (int s = 0; s < 4; ++s) {
        ah[s] = *reinterpret_cast<const bf16x8*>(&XhiS[arow][s * 32 + g * 8]);
        al[s] = *reinterpret_cast<const bf16x8*>(&XloS[arow][s * 32 + g * 8]);
    }

    f32x4 acc[8] = {};

    #pragma unroll
    for (int s = 0; s < 4; ++s)
        #pragma unroll
        for (int nf = 0; nf < 8; ++nf) {
            bf16x8 bb = *reinterpret_cast<const bf16x8*>(&WS[nf * 16 + nr][s * 32 + g * 8]);
            acc[nf] = __builtin_amdgcn_mfma_f32_16x16x32_bf16(ah[s], bb, acc[nf], 0, 0, 0);
            acc[nf] = __builtin_amdgcn_mfma_f32_16x16x32_bf16(al[s], bb, acc[nf], 0, 0, 0);
        }
    __syncthreads();
    #pragma unroll
    for (int u = 0; u < 16; ++u) {
        int q = u * 128 + t;
        int n = q >> 4, ck = q & 15;
        *reinterpret_cast<uint4*>(&WS[n][ck * 8]) =
            *reinterpret_cast<const uint4*>(Wt_lo + (size_t)n * IN_DIM + kc * KC + ck * 8);
    }
    __syncthreads();
    #pragma unroll
    for (int s = 0; s < 4; ++s)
        #pragma unroll
        for (int nf = 0; nf < 8; ++nf) {
            bf16x8 bb = *reinterpret_cast<const bf16x8*>(&WS[nf * 16 + nr][s * 32 + g * 8]);
            acc[nf] = __builtin_amdgcn_mfma_f32_16x16x32_bf16(ah[s], bb, acc[nf], 0, 0, 0);
        }

    float* part = partials + (size_t)kc * NN * HID;
    #pragma unroll
    for (int nf = 0; nf < 8; ++nf)
        #pragma unroll
        for (int r = 0; r < 4; ++r)
            part[(size_t)(m0 + w * 16 + g * 4 + r) * HID + nf * 16 + nr] = acc[nf][r];
}

// ---------------------------------------------------------------------------
// 3c) reduce split-K partials + bias + relu -> rf bf16 (cols 0:128) + P1_0/P2_0
__global__ void embed_reduce(const float* __restrict__ partials, const float* __restrict__ bias,
                             const float* __restrict__ d1, const float* __restrict__ d2,
                             uint16_t* __restrict__ rfb, uint16_t* __restrict__ P1,
                             uint16_t* __restrict__ P2) {
    int idx = blockIdx.x * blockDim.x + threadIdx.x;
    size_t off = (size_t)idx * 4;
    int row = (int)(off >> 7);
    int col = (int)(off & 127);

    float4 s = make_float4(0.f, 0.f, 0.f, 0.f);
    #pragma unroll
    for (int kc = 0; kc < KS; ++kc) {
        float4 p = *reinterpret_cast<const float4*>(partials + (size_t)kc * NN * HID + off);
        s.x += p.x; s.y += p.y; s.z += p.z; s.w += p.w;
    }
    float4 bv = *reinterpret_cast<const float4*>(bias + col);
    float4 v;
    v.x = fmaxf(s.x + bv.x, 0.f);
    v.y = fmaxf(s.y + bv.y, 0.f);
    v.z = fmaxf(s.z + bv.z, 0.f);
    v.w = fmaxf(s.w + bv.w, 0.f);

    uint2 rv;
    rv.x = packbf(v.x, v.y); rv.y = packbf(v.z, v.w);
    *reinterpret_cast<uint2*>(rfb + (size_t)row * RF + col) = rv;

    float s1 = d1[row], s2 = d2[row];
    ushort4 q;
    q.x = f2bf(s1 * v.x); q.y = f2bf(s1 * v.y); q.z = f2bf(s1 * v.z); q.w = f2bf(s1 * v.w);
    *reinterpret_cast<ushort4*>(P1 + (size_t)row * HID + col) = q;
    q.x = f2bf(s2 * v.x); q.y = f2bf(s2 * v.y); q.z = f2bf(s2 * v.z); q.w = f2bf(s2 * v.w);
    *reinterpret_cast<ushort4*>(P2 + (size_t)row * HID + col) = q;
}

// ---------------------------------------------------------------------------
// 4a) hop-1 gather. Wave task gw: row i = gw>>1, mat = gw&1. No barriers.
//     adj fetch is wave-uniform (readfirstlane'd i/mat) -> scalar s_load of
//     4 packed uint16 indices; lanes extract their group's index with shift.
__global__ __launch_bounds__(256) void gather_k1(
    const uint16_t* __restrict__ adj1, const uint16_t* __restrict__ adj2,
    const int* __restrict__ deg1p, const int* __restrict__ deg2p,
    const uint32_t* __restrict__ P10, const uint32_t* __restrict__ P20,
    const float* __restrict__ d1, const float* __restrict__ d2,
    uint16_t* __restrict__ rfb, uint16_t* __restrict__ P11, uint16_t* __restrict__ P21)
{
    int lane = threadIdx.x & 63;
    int gw   = __builtin_amdgcn_readfirstlane((blockIdx.x * 256 + threadIdx.x) >> 6);
    int i    = gw >> 1;
    int mat  = gw & 1;
    int nb = lane >> 4, cq = lane & 15;
    int shamt = lane & 48;               // nb*16

    const uint16_t* adj = mat ? adj2 + (size_t)i * CAP2 : adj1 + (size_t)i * CAP1;
    int n = (mat ? deg2p : deg1p)[i];
    const uint32_t* P = mat ? P20 : P10;

    f32x2 acc[4] = {};
    #pragma unroll 8
    for (int m = 0; m < n; m += 4) {
        uint64_t aw = *reinterpret_cast<const uint64_t*>(adj + m);   // uniform -> s_load
        int j = (int)((uint32_t)(aw >> shamt) & 0xffffu);
        uint4 u = *reinterpret_cast<const uint4*>(P + (size_t)j * 64 + cq * 4);
        acc[0] += (f32x2){__uint_as_float(u.x << 16), __uint_as_float(u.x & 0xffff0000u)};
        acc[1] += (f32x2){__uint_as_float(u.y << 16), __uint_as_float(u.y & 0xffff0000u)};
        acc[2] += (f32x2){__uint_as_float(u.z << 16), __uint_as_float(u.z & 0xffff0000u)};
        acc[3] += (f32x2){__uint_as_float(u.w << 16), __uint_as_float(u.w & 0xffff0000u)};
    }
    #pragma unroll
    for (int k = 0; k < 4; ++k) {
        acc[k].x += __shfl_xor(acc[k].x, 16); acc[k].y += __shfl_xor(acc[k].y, 16);
        acc[k].x += __shfl_xor(acc[k].x, 32); acc[k].y += __shfl_xor(acc[k].y, 32);
    }

    if (nb == 0) {
        float di = (mat ? d2 : d1)[i];
        float o[8];
        #pragma unroll
        for (int k = 0; k < 4; ++k) { o[2 * k] = di * acc[k].x; o[2 * k + 1] = di * acc[k].y; }

        uint4 rv;
        rv.x = packbf(o[0], o[1]); rv.y = packbf(o[2], o[3]);
        rv.z = packbf(o[4], o[5]); rv.w = packbf(o[6], o[7]);
        *reinterpret_cast<uint4*>(rfb + (size_t)i * RF + 128 + mat * 128 + cq * 8) = rv;

        float s1 = d1[i], s2 = d2[i];
        uint32_t* q1 = reinterpret_cast<uint32_t*>(P11) + (size_t)i * 128 + mat * 64 + cq * 4;
        uint32_t* q2 = reinterpret_cast<uint32_t*>(P21) + (size_t)i * 128 + mat * 64 + cq * 4;
        uint4 v1, v2;
        v1.x = packbf(s1 * o[0], s1 * o[1]); v1.y = packbf(s1 * o[2], s1 * o[3]);
        v1.z = packbf(s1 * o[4], s1 * o[5]); v1.w = packbf(s1 * o[6], s1 * o[7]);
        v2.x = packbf(s2 * o[0], s2 * o[1]); v2.y = packbf(s2 * o[2], s2 * o[3]);
        v2.z = packbf(s2 * o[4], s2 * o[5]); v2.w = packbf(s2 * o[6], s2 * o[7]);
        *reinterpret_cast<uint4*>(q1) = v1;
        *reinterpret_cast<uint4*>(q2) = v2;
    }
}

// ---------------------------------------------------------------------------
// 4b) hop-2 gather, standalone, barrier-free, segment-grouped, scalar adj.
//     Grid 4096 blocks: seg = b>>10 (mat=seg>>1, half=seg&1), row = (b&1023)*4+wv.
__global__ __launch_bounds__(256) void gather_k2(
    const uint16_t* __restrict__ adj1, const uint16_t* __restrict__ adj2,
    const int* __restrict__ deg1p, const int* __restrict__ deg2p,
    const uint32_t* __restrict__ P11, const uint32_t* __restrict__ P21,
    const float* __restrict__ d1, const float* __restrict__ d2,
    uint16_t* __restrict__ rfb)
{
    int wv   = threadIdx.x >> 6;
    int lane = threadIdx.x & 63;
    int seg  = blockIdx.x >> 10;
    int i    = __builtin_amdgcn_readfirstlane((blockIdx.x & 1023) * 4 + wv);
    int mat  = seg >> 1;
    int half = seg & 1;
    int nb = lane >> 4, cq = lane & 15;
    int shamt = lane & 48;               // nb*16

    const uint16_t* adj = mat ? adj2 + (size_t)i * CAP2 : adj1 + (size_t)i * CAP1;
    int n = (mat ? deg2p : deg1p)[i];
    const uint32_t* P = (mat ? P21 : P11) + half * 64 + cq * 4;

    f32x2 acc[4] = {};
    #pragma unroll 8
    for (int m = 0; m < n; m += 4) {
        uint64_t aw = *reinterpret_cast<const uint64_t*>(adj + m);   // uniform -> s_load
        int j = (int)((uint32_t)(aw >> shamt) & 0xffffu);
        uint4 u = *reinterpret_cast<const uint4*>(P + (size_t)j * 128);
        acc[0] += (f32x2){__uint_as_float(u.x << 16), __uint_as_float(u.x & 0xffff0000u)};
        acc[1] += (f32x2){__uint_as_float(u.y << 16), __uint_as_float(u.y & 0xffff0000u)};
        acc[2] += (f32x2){__uint_as_float(u.z << 16), __uint_as_float(u.z & 0xffff0000u)};
        acc[3] += (f32x2){__uint_as_float(u.w << 16), __uint_as_float(u.w & 0xffff0000u)};
    }
    #pragma unroll
    for (int k = 0; k < 4; ++k) {
        acc[k].x += __shfl_xor(acc[k].x, 16); acc[k].y += __shfl_xor(acc[k].y, 16);
        acc[k].x += __shfl_xor(acc[k].x, 32); acc[k].y += __shfl_xor(acc[k].y, 32);
    }

    if (nb == 0) {
        float di = (mat ? d2 : d1)[i];
        int colbase = 384 + mat * 256 + half * 128 + cq * 8;
        uint4 rv;
        rv.x = packbf(di * acc[0].x, di * acc[0].y);
        rv.y = packbf(di * acc[1].x, di * acc[1].y);
        rv.z = packbf(di * acc[2].x, di * acc[2].y);
        rv.w = packbf(di * acc[3].x, di * acc[3].y);
        *reinterpret_cast<uint4*>(rfb + (size_t)i * RF + colbase) = rv;
    }
}

// ---------------------------------------------------------------------------
// 5) classifier GEMM over bf16 rf: out = rf @ Wc + bc. Wave-per-row.
__global__ __launch_bounds__(256) void cls_bf(
    const uint16_t* __restrict__ rfb, const float* __restrict__ Wc,
    const float* __restrict__ bc, float* __restrict__ out)
{
    int wave = threadIdx.x >> 6;
    int lane = threadIdx.x & 63;
    int row  = blockIdx.x * 4 + wave;

    const uint32_t* rp = reinterpret_cast<const uint32_t*>(rfb + (size_t)row * RF);
    float acc[10] = {};
    #pragma unroll
    for (int k7 = 0; k7 < 7; ++k7) {
        int k = k7 * 64 + lane;          // uint index 0..447 (col pair 2k,2k+1)
        uint32_t u = rp[k];
        float x0 = __uint_as_float(u << 16);
        float x1 = __uint_as_float(u & 0xffff0000u);
        const float* w = Wc + (size_t)k * 20;
        #pragma unroll
        for (int c = 0; c < 10; ++c) acc[c] += x0 * w[c] + x1 * w[10 + c];
    }
    #pragma unroll
    for (int c = 0; c < 10; ++c)
        #pragma unroll
        for (int off = 32; off; off >>= 1) acc[c] += __shfl_down(acc[c], off);

    if (lane == 0) {
        #pragma unroll
        for (int c = 0; c < 10; ++c) out[(size_t)row * 10 + c] = acc[c] + bc[c];
    }
}

// ---------------------------------------------------------------------------
extern "C" void kernel_launch(void* const* d_in, const int* in_sizes, int n_in,
                              void* d_out, int out_size, void* d_ws, size_t ws_size,
                              hipStream_t stream) {
    const float* X       = (const float*)d_in[0];
    const int*   ei      = (const int*)d_in[1];
    const float* W_embed = (const float*)d_in[2];
    const float* b_embed = (const float*)d_in[3];
    const float* W_cls   = (const float*)d_in[4];
    const float* b_cls   = (const float*)d_in[5];
    float* out = (float*)d_out;

    int nE = in_sizes[1] / 2;

    // workspace layout (all 16B-aligned)
    uint32_t* Abits = (uint32_t*)d_ws;                         // 2 MB
    float* d1 = (float*)(Abits + (size_t)NN * NW);             // 16 KB
    float* d2 = d1 + NN;                                       // 16 KB
    uint16_t* rfb = (uint16_t*)(d2 + NN);                      // 7.34 MB bf16 [NN][RF]
    uint16_t* P1_0 = rfb + (size_t)NN * RF;                    // [NN+1][128] bf16
    uint16_t* P2_0 = P1_0 + (size_t)(NN + 1) * HID;
    uint16_t* P1_1 = P2_0 + (size_t)(NN + 1) * HID;            // [NN+1][256] bf16
    uint16_t* P2_1 = P1_1 + (size_t)(NN + 1) * 256;
    uint16_t* Wt_hi = P2_1 + (size_t)(NN + 1) * 256;           // 256 KB
    uint16_t* Wt_lo = Wt_hi + (size_t)HID * IN_DIM;            // 256 KB
    float* partials = (float*)(Wt_lo + (size_t)HID * IN_DIM);  // 16 MB [KS][NN][128]
    uint16_t* adj1 = (uint16_t*)(partials + (size_t)KS * NN * HID); // 512 KB
    uint16_t* adj2 = adj1 + (size_t)NN * CAP1;                 // 8 MB
    int* deg1p = (int*)(adj2 + (size_t)NN * CAP2);             // 16 KB
    int* deg2p = deg1p + NN;                                   // 16 KB

    prep<<<641, 256, 0, stream>>>(Abits, (uint32_t*)P1_0, (uint32_t*)P2_0,
                                  (uint32_t*)P1_1, (uint32_t*)P2_1,
                                  W_embed, Wt_hi, Wt_lo);
    scatter_edges<<<(nE + 255) / 256, 256, 0, stream>>>(ei, Abits, nE);
    twohop2<<<NN / 4, 256, 0, stream>>>(Abits, adj1, adj2, deg1p, deg2p, d1, d2);

    embed_mfma<<<dim3(NN / 32, KS), 128, 0, stream>>>(X, Wt_hi, Wt_lo, partials);
    embed_reduce<<<(NN * HID / 4) / 256, 256, 0, stream>>>(partials, b_embed, d1, d2,
                                                           rfb, P1_0, P2_0);

    gather_k1<<<NN * 2 * 64 / 256, 256, 0, stream>>>(
        adj1, adj2, deg1p, deg2p,
        (const uint32_t*)P1_0, (const uint32_t*)P2_0, d1, d2,
        rfb, P1_1, P2_1);
    gather_k2<<<NN * 4 * 64 / 256, 256, 0, stream>>>(
        adj1, adj2, deg1p, deg2p,
        (const uint32_t*)P1_1, (const uint32_t*)P2_1, d1, d2, rfb);

    cls_bf<<<NN / 4, 256, 0, stream>>>(rfb, W_cls, b_cls, out);
}